// Round 6
// baseline (1993.560 us; speedup 1.0000x reference)
//
#include <hip/hip_runtime.h>

#define DEVI __device__ __forceinline__

typedef __attribute__((ext_vector_type(8))) short short8;
typedef __attribute__((ext_vector_type(4))) float f32x4;

constexpr int Bn = 8, Tn = 1024, Cn = 512, Hn = 8, DHn = 64, Ln = 6, ODn = 768;
constexpr int Mn = Bn * Tn;  // 8192 rows

// ---------- helpers ----------
DEVI short f2bs(float f) {  // fp32 -> bf16 raw bits, round-to-nearest-even
  unsigned u = __builtin_bit_cast(unsigned, f);
  unsigned r = (u + 0x7FFFu + ((u >> 16) & 1u)) >> 16;
  return (short)r;
}

DEVI float gelu_f(float v) {  // exact GELU
  return 0.5f * v * (1.0f + erff(v * 0.70710678118654752f));
}

DEVI void gload_lds16(const void* gp, void* lp) {  // 16B/lane global->LDS DMA
  __builtin_amdgcn_global_load_lds(
      (const __attribute__((address_space(1))) unsigned*)gp,
      (__attribute__((address_space(3))) unsigned*)lp, 16, 0, 0);
}

// ---------- weight cast + transpose: fp32 [K,N] -> bf16 [N,K] ----------
__global__ __launch_bounds__(256) void wtrans_kernel(
    const float* __restrict__ W, short* __restrict__ Wt, int K, int N) {
  __shared__ float tile[32][33];
  const int tx = threadIdx.x & 31, ty = threadIdx.x >> 5;  // 32 x 8
  const int k0 = blockIdx.y * 32, n0 = blockIdx.x * 32;
#pragma unroll
  for (int i = 0; i < 4; ++i)
    tile[ty + i * 8][tx] = W[(size_t)(k0 + ty + i * 8) * N + n0 + tx];
  __syncthreads();
#pragma unroll
  for (int i = 0; i < 4; ++i)
    Wt[(size_t)(n0 + ty + i * 8) * K + k0 + tx] = f2bs(tile[tx][ty + i * 8]);
}

// ---------- elementwise fp32 -> bf16 ----------
__global__ __launch_bounds__(256) void cast_kernel(
    const float* __restrict__ in, short* __restrict__ out) {
  const int i = blockIdx.x * 256 + threadIdx.x;
  out[i] = f2bs(in[i]);
}

// ---------- LayerNorm (one 256-thread block per 512-elem row) ----------
template <typename OUTT>
__global__ __launch_bounds__(256) void ln_kernel(
    const float* __restrict__ x, const float* __restrict__ w,
    const float* __restrict__ bb, OUTT* __restrict__ out) {
  const int row = blockIdx.x, tid = threadIdx.x;
  const float* xr = x + (size_t)row * Cn;
  const float v0 = xr[tid], v1 = xr[tid + 256];
  float s = v0 + v1, s2 = v0 * v0 + v1 * v1;
#pragma unroll
  for (int m = 1; m < 64; m <<= 1) {
    s += __shfl_xor(s, m);
    s2 += __shfl_xor(s2, m);
  }
  __shared__ float red[8];
  const int wave = tid >> 6, lane = tid & 63;
  if (lane == 0) { red[wave] = s; red[4 + wave] = s2; }
  __syncthreads();
  s = red[0] + red[1] + red[2] + red[3];
  s2 = red[4] + red[5] + red[6] + red[7];
  const float mu = s * (1.0f / Cn);
  const float var = s2 * (1.0f / Cn) - mu * mu;
  const float rstd = rsqrtf(var + 1e-5f);
  const float o0 = (v0 - mu) * rstd * w[tid] + bb[tid];
  const float o1 = (v1 - mu) * rstd * w[tid + 256] + bb[tid + 256];
  if constexpr (sizeof(OUTT) == 2) {
    out[(size_t)row * Cn + tid] = f2bs(o0);
    out[(size_t)row * Cn + tid + 256] = f2bs(o1);
  } else {
    out[(size_t)row * Cn + tid] = o0;
    out[(size_t)row * Cn + tid + 256] = o1;
  }
}

// ---------- bf16 MFMA GEMM: out[M,N] = A[M,K] @ Bt[N,K]^T + bias ----------
// EPI: 0 = bf16 out, 1 = gelu->bf16, 2 = gelu + pos_emb -> fp32 resid,
//      3 = fp32 resid += out
template <int EPI>
__global__ __launch_bounds__(256) void gemm_kernel(
    const short* __restrict__ A, const short* __restrict__ Bt,
    const float* __restrict__ bias, short* __restrict__ outb,
    float* __restrict__ resid, const float* __restrict__ pos, int K, int N) {
  __shared__ __align__(16) short As[128 * 64];
  __shared__ __align__(16) short Bs[128 * 64];
  const int tid = threadIdx.x;
  const int lane = tid & 63;
  const int wave = tid >> 6;
  const int m0 = blockIdx.y * 128;
  const int n0 = blockIdx.x * 128;
  const int wr = (wave >> 1) * 64;
  const int wc = (wave & 1) * 64;
  const int lA = lane & 15;
  const int lB = (lane >> 4) * 8;

  f32x4 acc[4][4];
#pragma unroll
  for (int a = 0; a < 4; ++a)
#pragma unroll
    for (int b = 0; b < 4; ++b) acc[a][b] = f32x4{0.f, 0.f, 0.f, 0.f};

  const int rS = tid >> 3;          // 0..31 staged row
  const int cS = (tid & 7) * 8;     // staged k offset
  const short* Ag = A + (size_t)(m0 + rS) * K + cS;
  const short* Bg = Bt + (size_t)(n0 + rS) * K + cS;

  for (int kk = 0; kk < K; kk += 64) {
#pragma unroll
    for (int it = 0; it < 4; ++it) {
      gload_lds16(Ag + (size_t)it * 32 * K + kk, &As[it * 2048 + wave * 512]);
      gload_lds16(Bg + (size_t)it * 32 * K + kk, &Bs[it * 2048 + wave * 512]);
    }
    __syncthreads();
#pragma unroll
    for (int ks = 0; ks < 2; ++ks) {
      short8 af[4], bf[4];
#pragma unroll
      for (int i = 0; i < 4; ++i) {
        af[i] = *(const short8*)&As[(wr + i * 16 + lA) * 64 + ks * 32 + lB];
        bf[i] = *(const short8*)&Bs[(wc + i * 16 + lA) * 64 + ks * 32 + lB];
      }
#pragma unroll
      for (int mi = 0; mi < 4; ++mi)
#pragma unroll
        for (int ni = 0; ni < 4; ++ni)
          acc[mi][ni] = __builtin_amdgcn_mfma_f32_16x16x32_bf16(
              af[mi], bf[ni], acc[mi][ni], 0, 0, 0);
    }
    __syncthreads();
  }

#pragma unroll
  for (int mi = 0; mi < 4; ++mi) {
    const int row = m0 + wr + mi * 16 + (lane >> 4) * 4;
#pragma unroll
    for (int ni = 0; ni < 4; ++ni) {
      const int col = n0 + wc + ni * 16 + (lane & 15);
      const float bv = bias[col];
#pragma unroll
      for (int j = 0; j < 4; ++j) {
        const float v = acc[mi][ni][j] + bv;
        const size_t idx = (size_t)(row + j) * N + col;
        if constexpr (EPI == 0) {
          outb[idx] = f2bs(v);
        } else if constexpr (EPI == 1) {
          outb[idx] = f2bs(gelu_f(v));
        } else if constexpr (EPI == 2) {
          resid[idx] = gelu_f(v) + pos[(size_t)((row + j) & (Tn - 1)) * Cn + col];
        } else {
          resid[idx] += v;
        }
      }
    }
  }
}

// ---------- causal flash attention ----------
// grid: (T/128, B*H); block 256. Wave w owns 32 q-rows. KV tiles of 32.
__global__ __launch_bounds__(256) void attn_kernel(
    const short* __restrict__ q, const short* __restrict__ k,
    const short* __restrict__ v, short* __restrict__ y) {
  __shared__ __align__(16) short Kt[32 * 64];   // [kv][d]
  __shared__ __align__(16) short Vt[64 * 32];   // [d][kv] (transposed)
  __shared__ __align__(16) short Ps[4 * 32 * 32];  // per-wave P scratch
  const int tid = threadIdx.x, lane = tid & 63, wave = tid >> 6;
  const int qb = blockIdx.x;
  const int bh = blockIdx.y;
  const int b = bh >> 3, h = bh & 7;
  const int qw = qb * 128 + wave * 32;
  const short* qp = q + (size_t)b * Tn * Cn + h * DHn;
  const short* kp = k + (size_t)b * Tn * Cn + h * DHn;
  const short* vp = v + (size_t)b * Tn * Cn + h * DHn;
  short* yp = y + (size_t)b * Tn * Cn + h * DHn;
  const int lr = lane & 15;
  const int lg = lane >> 4;

  short8 qf[2][2];
#pragma unroll
  for (int rf = 0; rf < 2; ++rf)
#pragma unroll
    for (int ks = 0; ks < 2; ++ks)
      qf[rf][ks] =
          *(const short8*)(qp + (size_t)(qw + rf * 16 + lr) * Cn + ks * 32 + lg * 8);

  f32x4 o[2][4], mrun[2], lrun[2];
#pragma unroll
  for (int rf = 0; rf < 2; ++rf) {
#pragma unroll
    for (int vf = 0; vf < 4; ++vf) o[rf][vf] = f32x4{0.f, 0.f, 0.f, 0.f};
    mrun[rf] = f32x4{-3e38f, -3e38f, -3e38f, -3e38f};
    lrun[rf] = f32x4{0.f, 0.f, 0.f, 0.f};
  }

  const int ntb = qb * 4 + 4;           // tiles staged by the block
  const int ntw = qb * 4 + wave + 1;    // tiles this wave must compute
  const int svr = tid >> 3;             // V stage row 0..31
  const int svd = (tid & 7) * 8;        // V stage d base

  for (int kt = 0; kt < ntb; ++kt) {
    const int kbase = kt * 32;
    gload_lds16(kp + (size_t)(kbase + wave * 8 + (lane >> 3)) * Cn + (lane & 7) * 8,
                &Kt[wave * 512]);
    {
      short8 vv = *(const short8*)(vp + (size_t)(kbase + svr) * Cn + svd);
#pragma unroll
      for (int j = 0; j < 8; ++j) Vt[(svd + j) * 32 + svr] = vv[j];
    }
    __syncthreads();
    if (kt < ntw) {
      f32x4 s[2][2];
#pragma unroll
      for (int rf = 0; rf < 2; ++rf)
#pragma unroll
        for (int cf = 0; cf < 2; ++cf) s[rf][cf] = f32x4{0.f, 0.f, 0.f, 0.f};
#pragma unroll
      for (int ks = 0; ks < 2; ++ks) {
        short8 kf[2];
#pragma unroll
        for (int cf = 0; cf < 2; ++cf)
          kf[cf] = *(const short8*)&Kt[(cf * 16 + lr) * 64 + ks * 32 + lg * 8];
#pragma unroll
        for (int rf = 0; rf < 2; ++rf)
#pragma unroll
          for (int cf = 0; cf < 2; ++cf)
            s[rf][cf] = __builtin_amdgcn_mfma_f32_16x16x32_bf16(
                qf[rf][ks], kf[cf], s[rf][cf], 0, 0, 0);
      }
      short* Pw = &Ps[wave * 1024];
#pragma unroll
      for (int rf = 0; rf < 2; ++rf) {
        f32x4 tm;
#pragma unroll
        for (int j = 0; j < 4; ++j) {
          const int qrow = qw + rf * 16 + lg * 4 + j;
#pragma unroll
          for (int cf = 0; cf < 2; ++cf) {
            float sv = s[rf][cf][j] * 0.125f;
            if (kbase + cf * 16 + lr > qrow) sv = -1e30f;
            s[rf][cf][j] = sv;
          }
          tm[j] = fmaxf(s[rf][0][j], s[rf][1][j]);
        }
#pragma unroll
        for (int mm = 1; mm < 16; mm <<= 1)
#pragma unroll
          for (int j = 0; j < 4; ++j) tm[j] = fmaxf(tm[j], __shfl_xor(tm[j], mm));
        f32x4 mnew, corr, ps;
#pragma unroll
        for (int j = 0; j < 4; ++j) {
          mnew[j] = fmaxf(mrun[rf][j], tm[j]);
          corr[j] = __expf(mrun[rf][j] - mnew[j]);
          mrun[rf][j] = mnew[j];
        }
#pragma unroll
        for (int j = 0; j < 4; ++j) {
          const float p0 = __expf(s[rf][0][j] - mnew[j]);
          const float p1 = __expf(s[rf][1][j] - mnew[j]);
          s[rf][0][j] = p0;
          s[rf][1][j] = p1;
          ps[j] = p0 + p1;
        }
#pragma unroll
        for (int mm = 1; mm < 16; mm <<= 1)
#pragma unroll
          for (int j = 0; j < 4; ++j) ps[j] += __shfl_xor(ps[j], mm);
#pragma unroll
        for (int j = 0; j < 4; ++j) lrun[rf][j] = lrun[rf][j] * corr[j] + ps[j];
#pragma unroll
        for (int vf = 0; vf < 4; ++vf)
#pragma unroll
          for (int j = 0; j < 4; ++j) o[rf][vf][j] *= corr[j];
#pragma unroll
        for (int cf = 0; cf < 2; ++cf)
#pragma unroll
          for (int j = 0; j < 4; ++j)
            Pw[(rf * 16 + lg * 4 + j) * 32 + cf * 16 + lr] = f2bs(s[rf][cf][j]);
      }
      // same-wave LDS write->read: drain DS queue, fence compiler reordering
      asm volatile("s_waitcnt lgkmcnt(0)" ::: "memory");
      short8 pa[2], vb2[4];
#pragma unroll
      for (int rf = 0; rf < 2; ++rf)
        pa[rf] = *(const short8*)&Pw[(rf * 16 + lr) * 32 + lg * 8];
#pragma unroll
      for (int vf = 0; vf < 4; ++vf)
        vb2[vf] = *(const short8*)&Vt[(vf * 16 + lr) * 32 + lg * 8];
#pragma unroll
      for (int rf = 0; rf < 2; ++rf)
#pragma unroll
        for (int vf = 0; vf < 4; ++vf)
          o[rf][vf] = __builtin_amdgcn_mfma_f32_16x16x32_bf16(
              pa[rf], vb2[vf], o[rf][vf], 0, 0, 0);
    }
    __syncthreads();
  }
#pragma unroll
  for (int rf = 0; rf < 2; ++rf) {
    f32x4 inv;
#pragma unroll
    for (int j = 0; j < 4; ++j) inv[j] = 1.0f / lrun[rf][j];
#pragma unroll
    for (int vf = 0; vf < 4; ++vf)
#pragma unroll
      for (int j = 0; j < 4; ++j)
        yp[(size_t)(qw + rf * 16 + lg * 4 + j) * Cn + vf * 16 + lr] =
            f2bs(o[rf][vf][j] * inv[j]);
  }
}

// ---------- launch ----------
extern "C" void kernel_launch(void* const* d_in, const int* in_sizes, int n_in,
                              void* d_out, int out_size, void* d_ws, size_t ws_size,
                              hipStream_t stream) {
  const float* observations = (const float*)d_in[0];
  const float* obs_W = (const float*)d_in[1];
  const float* obs_b = (const float*)d_in[2];
  const float* pos_emb = (const float*)d_in[3];
  const float* ln1_w = (const float*)d_in[4];
  const float* ln1_b = (const float*)d_in[5];
  const float* Wq = (const float*)d_in[6];
  const float* bq = (const float*)d_in[7];
  const float* Wk = (const float*)d_in[8];
  const float* bk = (const float*)d_in[9];
  const float* Wv = (const float*)d_in[10];
  const float* bv = (const float*)d_in[11];
  const float* Wo = (const float*)d_in[12];
  const float* bo = (const float*)d_in[13];
  const float* ln2_w = (const float*)d_in[14];
  const float* ln2_b = (const float*)d_in[15];
  const float* W1 = (const float*)d_in[16];
  const float* b1 = (const float*)d_in[17];
  const float* W2 = (const float*)d_in[18];
  const float* b2 = (const float*)d_in[19];
  const float* lnf_w = (const float*)d_in[20];
  const float* lnf_b = (const float*)d_in[21];
  float* out = (float*)d_out;

  char* ws = (char*)d_ws;
  auto alloc = [&](size_t bytes) -> void* {
    void* p = (void*)ws;
    ws += (bytes + 255) & ~(size_t)255;
    return p;
  };
  float* xf = (float*)alloc((size_t)Mn * Cn * 4);
  short* hbf = (short*)alloc((size_t)Mn * Cn * 2);
  short* qbf = (short*)alloc((size_t)Mn * Cn * 2);
  short* kbf = (short*)alloc((size_t)Mn * Cn * 2);
  short* vbf = (short*)alloc((size_t)Mn * Cn * 2);
  short* ybf = (short*)alloc((size_t)Mn * Cn * 2);
  short* gbf = (short*)alloc((size_t)Mn * 4 * Cn * 2);
  short* obsbf = (short*)alloc((size_t)Mn * ODn * 2);
  short* obsWt = (short*)alloc((size_t)ODn * Cn * 2);
  short* wqT = (short*)alloc((size_t)Ln * Cn * Cn * 2);
  short* wkT = (short*)alloc((size_t)Ln * Cn * Cn * 2);
  short* wvT = (short*)alloc((size_t)Ln * Cn * Cn * 2);
  short* woT = (short*)alloc((size_t)Ln * Cn * Cn * 2);
  short* w1T = (short*)alloc((size_t)Ln * Cn * 4 * Cn * 2);
  short* w2T = (short*)alloc((size_t)Ln * Cn * 4 * Cn * 2);
  if ((size_t)(ws - (char*)d_ws) > ws_size) return;  // ws too small: bail

  const size_t WCC = (size_t)Cn * Cn;        // 262144
  const size_t WCF = (size_t)Cn * 4 * Cn;    // 1048576

  // weight casts/transposes
  wtrans_kernel<<<dim3(Cn / 32, ODn / 32), 256, 0, stream>>>(obs_W, obsWt, ODn, Cn);
  for (int i = 0; i < Ln; ++i) {
    wtrans_kernel<<<dim3(16, 16), 256, 0, stream>>>(Wq + i * WCC, wqT + i * WCC, Cn, Cn);
    wtrans_kernel<<<dim3(16, 16), 256, 0, stream>>>(Wk + i * WCC, wkT + i * WCC, Cn, Cn);
    wtrans_kernel<<<dim3(16, 16), 256, 0, stream>>>(Wv + i * WCC, wvT + i * WCC, Cn, Cn);
    wtrans_kernel<<<dim3(16, 16), 256, 0, stream>>>(Wo + i * WCC, woT + i * WCC, Cn, Cn);
    wtrans_kernel<<<dim3(64, 16), 256, 0, stream>>>(W1 + i * WCF, w1T + i * WCF, Cn, 4 * Cn);
    wtrans_kernel<<<dim3(16, 64), 256, 0, stream>>>(W2 + i * WCF, w2T + i * WCF, 4 * Cn, Cn);
  }
  cast_kernel<<<(Mn * ODn) / 256, 256, 0, stream>>>(observations, obsbf);

  // obs embedding: gelu(obs@W+b) + pos -> xf (fp32)
  gemm_kernel<2><<<dim3(Cn / 128, Mn / 128), 256, 0, stream>>>(
      obsbf, obsWt, obs_b, nullptr, xf, pos_emb, ODn, Cn);

  for (int i = 0; i < Ln; ++i) {
    ln_kernel<short><<<Mn, 256, 0, stream>>>(xf, ln1_w + i * Cn, ln1_b + i * Cn, hbf);
    gemm_kernel<0><<<dim3(4, 64), 256, 0, stream>>>(hbf, wqT + i * WCC, bq + i * Cn,
                                                    qbf, nullptr, nullptr, Cn, Cn);
    gemm_kernel<0><<<dim3(4, 64), 256, 0, stream>>>(hbf, wkT + i * WCC, bk + i * Cn,
                                                    kbf, nullptr, nullptr, Cn, Cn);
    gemm_kernel<0><<<dim3(4, 64), 256, 0, stream>>>(hbf, wvT + i * WCC, bv + i * Cn,
                                                    vbf, nullptr, nullptr, Cn, Cn);
    attn_kernel<<<dim3(Tn / 128, Bn * Hn), 256, 0, stream>>>(qbf, kbf, vbf, ybf);
    gemm_kernel<3><<<dim3(4, 64), 256, 0, stream>>>(ybf, woT + i * WCC, bo + i * Cn,
                                                    nullptr, xf, nullptr, Cn, Cn);
    ln_kernel<short><<<Mn, 256, 0, stream>>>(xf, ln2_w + i * Cn, ln2_b + i * Cn, hbf);
    gemm_kernel<1><<<dim3(16, 64), 256, 0, stream>>>(hbf, w1T + i * WCF, b1 + i * 4 * Cn,
                                                     gbf, nullptr, nullptr, Cn, 4 * Cn);
    gemm_kernel<3><<<dim3(4, 64), 256, 0, stream>>>(gbf, w2T + i * WCF, b2 + i * Cn,
                                                    nullptr, xf, nullptr, 4 * Cn, Cn);
  }
  ln_kernel<float><<<Mn, 256, 0, stream>>>(xf, lnf_w, lnf_b, out);
}

// Round 7
// 1762.078 us; speedup vs baseline: 1.1314x; 1.1314x over previous
//
#include <hip/hip_runtime.h>

#define DEVI __device__ __forceinline__

typedef __attribute__((ext_vector_type(8))) short short8;
typedef __attribute__((ext_vector_type(4))) short sh4;
typedef __attribute__((ext_vector_type(4))) float f32x4;

constexpr int Bn = 8, Tn = 1024, Cn = 512, Hn = 8, DHn = 64, Ln = 6, ODn = 768;
constexpr int Mn = Bn * Tn;   // 8192 rows
constexpr int SQk = 1536;     // packed qkv row stride

// ---------- helpers ----------
DEVI short f2bs(float f) {  // fp32 -> bf16 raw bits, round-to-nearest-even
  unsigned u = __builtin_bit_cast(unsigned, f);
  unsigned r = (u + 0x7FFFu + ((u >> 16) & 1u)) >> 16;
  return (short)r;
}

DEVI float gelu_f(float v) {  // exact GELU
  return 0.5f * v * (1.0f + erff(v * 0.70710678118654752f));
}

DEVI void gload_lds16(const void* gp, void* lp) {  // 16B/lane global->LDS DMA
  __builtin_amdgcn_global_load_lds(
      (const __attribute__((address_space(1))) unsigned*)gp,
      (__attribute__((address_space(3))) unsigned*)lp, 16, 0, 0);
}

DEVI short8 ld8(const short* p) {  // 8B-aligned 16-byte LDS read (2 x b64)
  sh4 a = *(const sh4*)p;
  sh4 b = *(const sh4*)(p + 4);
  return __builtin_shufflevector(a, b, 0, 1, 2, 3, 4, 5, 6, 7);
}

// ---------- batched weight cast+transpose fp32 [K,N] -> bf16 [N,K] ----------
// 24 C x C matrices: z -> (layer, which); q/k/v go packed into wqkvT rows.
__global__ __launch_bounds__(256) void wtrans4_kernel(
    const float* __restrict__ Wq, const float* __restrict__ Wk,
    const float* __restrict__ Wv, const float* __restrict__ Wo,
    short* __restrict__ wqkvT, short* __restrict__ woT) {
  const int z = blockIdx.z, i = z >> 2, which = z & 3;
  const size_t WCC = (size_t)Cn * Cn;
  const float* W = (which == 0) ? Wq : (which == 1) ? Wk : (which == 2) ? Wv : Wo;
  W += (size_t)i * WCC;
  short* dst = (which < 3) ? (wqkvT + (size_t)i * 3 * WCC + (size_t)which * WCC)
                           : (woT + (size_t)i * WCC);
  __shared__ float tile[32][33];
  const int tx = threadIdx.x & 31, ty = threadIdx.x >> 5;
  const int k0 = blockIdx.y * 32, n0 = blockIdx.x * 32;
#pragma unroll
  for (int q = 0; q < 4; ++q)
    tile[ty + q * 8][tx] = W[(size_t)(k0 + ty + q * 8) * Cn + n0 + tx];
  __syncthreads();
#pragma unroll
  for (int q = 0; q < 4; ++q)
    dst[(size_t)(n0 + ty + q * 8) * Cn + k0 + tx] = f2bs(tile[tx][ty + q * 8]);
}

// layered generic transpose (obs_W, W1, W2) — z = layer
__global__ __launch_bounds__(256) void wtransL_kernel(
    const float* __restrict__ W, short* __restrict__ Wt, int K, int N) {
  const int l = blockIdx.z;
  W += (size_t)l * K * N;
  Wt += (size_t)l * K * N;
  __shared__ float tile[32][33];
  const int tx = threadIdx.x & 31, ty = threadIdx.x >> 5;
  const int k0 = blockIdx.y * 32, n0 = blockIdx.x * 32;
#pragma unroll
  for (int q = 0; q < 4; ++q)
    tile[ty + q * 8][tx] = W[(size_t)(k0 + ty + q * 8) * N + n0 + tx];
  __syncthreads();
#pragma unroll
  for (int q = 0; q < 4; ++q)
    Wt[(size_t)(n0 + ty + q * 8) * K + k0 + tx] = f2bs(tile[tx][ty + q * 8]);
}

// concat bq/bk/bv -> bqkv [L][1536]
__global__ __launch_bounds__(256) void bcat_kernel(
    const float* __restrict__ bq, const float* __restrict__ bk,
    const float* __restrict__ bv, float* __restrict__ bqkv) {
  const int i = blockIdx.x * 256 + threadIdx.x;  // 0..6*1536-1
  const int l = i / 1536, c = i - l * 1536;
  float v = (c < 512) ? bq[l * 512 + c]
                      : (c < 1024) ? bk[l * 512 + c - 512] : bv[l * 512 + c - 1024];
  bqkv[i] = v;
}

// ---------- elementwise fp32 -> bf16 ----------
__global__ __launch_bounds__(256) void cast_kernel(
    const float* __restrict__ in, short* __restrict__ out) {
  const int i = blockIdx.x * 256 + threadIdx.x;
  out[i] = f2bs(in[i]);
}

// ---------- LayerNorm (one 256-thread block per 512-elem row) ----------
template <typename OUTT>
__global__ __launch_bounds__(256) void ln_kernel(
    const float* __restrict__ x, const float* __restrict__ w,
    const float* __restrict__ bb, OUTT* __restrict__ out) {
  const int row = blockIdx.x, tid = threadIdx.x;
  const float* xr = x + (size_t)row * Cn;
  const float v0 = xr[tid], v1 = xr[tid + 256];
  float s = v0 + v1, s2 = v0 * v0 + v1 * v1;
#pragma unroll
  for (int m = 1; m < 64; m <<= 1) {
    s += __shfl_xor(s, m);
    s2 += __shfl_xor(s2, m);
  }
  __shared__ float red[8];
  const int wave = tid >> 6, lane = tid & 63;
  if (lane == 0) { red[wave] = s; red[4 + wave] = s2; }
  __syncthreads();
  s = red[0] + red[1] + red[2] + red[3];
  s2 = red[4] + red[5] + red[6] + red[7];
  const float mu = s * (1.0f / Cn);
  const float var = s2 * (1.0f / Cn) - mu * mu;
  const float rstd = rsqrtf(var + 1e-5f);
  const float o0 = (v0 - mu) * rstd * w[tid] + bb[tid];
  const float o1 = (v1 - mu) * rstd * w[tid + 256] + bb[tid + 256];
  if constexpr (sizeof(OUTT) == 2) {
    out[(size_t)row * Cn + tid] = f2bs(o0);
    out[(size_t)row * Cn + tid + 256] = f2bs(o1);
  } else {
    out[(size_t)row * Cn + tid] = o0;
    out[(size_t)row * Cn + tid + 256] = o1;
  }
}

// ---------- bf16 MFMA GEMM: out[M,N] = A[M,K] @ Bt[N,K]^T + bias ----------
// EPI: 0 = bf16 out, 1 = gelu->bf16, 2 = gelu + pos_emb -> fp32 resid,
//      3 = fp32 resid += out  (KS>1: atomicAdd, bias only on z==0)
template <int EPI, int KS>
__global__ __launch_bounds__(256) void gemm_kernel(
    const short* __restrict__ A, const short* __restrict__ Bt,
    const float* __restrict__ bias, short* __restrict__ outb,
    float* __restrict__ resid, const float* __restrict__ pos, int K, int N) {
  __shared__ __align__(16) short As[128 * 64];
  __shared__ __align__(16) short Bs[128 * 64];
  const int tid = threadIdx.x;
  const int lane = tid & 63;
  const int wave = tid >> 6;
  const int m0 = blockIdx.y * 128;
  const int n0 = blockIdx.x * 128;
  const int z = (KS > 1) ? blockIdx.z : 0;
  const int Ksl = K / KS;
  const int wr = (wave >> 1) * 64;
  const int wc = (wave & 1) * 64;
  const int lA = lane & 15;
  const int lB = (lane >> 4) * 8;

  f32x4 acc[4][4];
#pragma unroll
  for (int a = 0; a < 4; ++a)
#pragma unroll
    for (int b = 0; b < 4; ++b) acc[a][b] = f32x4{0.f, 0.f, 0.f, 0.f};

  const int rS = tid >> 3;          // 0..31 staged row
  const int cS = (tid & 7) * 8;     // staged k offset
  const short* Ag = A + (size_t)(m0 + rS) * K + cS;
  const short* Bg = Bt + (size_t)(n0 + rS) * K + cS;

  for (int kk = z * Ksl; kk < z * Ksl + Ksl; kk += 64) {
#pragma unroll
    for (int it = 0; it < 4; ++it) {
      gload_lds16(Ag + (size_t)it * 32 * K + kk, &As[it * 2048 + wave * 512]);
      gload_lds16(Bg + (size_t)it * 32 * K + kk, &Bs[it * 2048 + wave * 512]);
    }
    __syncthreads();
#pragma unroll
    for (int ks = 0; ks < 2; ++ks) {
      short8 af[4], bf[4];
#pragma unroll
      for (int i = 0; i < 4; ++i) {
        af[i] = *(const short8*)&As[(wr + i * 16 + lA) * 64 + ks * 32 + lB];
        bf[i] = *(const short8*)&Bs[(wc + i * 16 + lA) * 64 + ks * 32 + lB];
      }
#pragma unroll
      for (int mi = 0; mi < 4; ++mi)
#pragma unroll
        for (int ni = 0; ni < 4; ++ni)
          acc[mi][ni] = __builtin_amdgcn_mfma_f32_16x16x32_bf16(
              af[mi], bf[ni], acc[mi][ni], 0, 0, 0);
    }
    __syncthreads();
  }

#pragma unroll
  for (int mi = 0; mi < 4; ++mi) {
    const int row = m0 + wr + mi * 16 + (lane >> 4) * 4;
#pragma unroll
    for (int ni = 0; ni < 4; ++ni) {
      const int col = n0 + wc + ni * 16 + (lane & 15);
      const float bv = (KS == 1 || z == 0) ? bias[col] : 0.f;
#pragma unroll
      for (int j = 0; j < 4; ++j) {
        const float v = acc[mi][ni][j] + bv;
        const size_t idx = (size_t)(row + j) * N + col;
        if constexpr (EPI == 0) {
          outb[idx] = f2bs(v);
        } else if constexpr (EPI == 1) {
          outb[idx] = f2bs(gelu_f(v));
        } else if constexpr (EPI == 2) {
          resid[idx] = gelu_f(v) + pos[(size_t)((row + j) & (Tn - 1)) * Cn + col];
        } else {
          if constexpr (KS > 1) atomicAdd(&resid[idx], v);
          else resid[idx] += v;
        }
      }
    }
  }
}

// ---------- causal flash attention ----------
// grid: (T/128, B*H); block 256. Wave w owns 32 q-rows. KV tiles of 64,
// double-buffered; K source-granule XOR swizzle; padded Vt/Ps strides.
__global__ __launch_bounds__(256) void attn_kernel(
    const short* __restrict__ qkv, short* __restrict__ y) {
  __shared__ __align__(16) short Kt[2][64 * 64];   // linear, swizzled granules
  __shared__ __align__(16) short Vt[2][64 * 68];   // [d][kv] pad->68
  __shared__ __align__(16) short Ps[4][32 * 68];   // per-wave P, pad->68
  const int tid = threadIdx.x, lane = tid & 63, wave = tid >> 6;
  const int qb = blockIdx.x;
  const int bh = blockIdx.y;
  const int b = bh >> 3, h = bh & 7;
  const int qw = qb * 128 + wave * 32;
  const short* qp = qkv + (size_t)b * Tn * SQk + h * DHn;
  const short* kp = qp + 512;
  const short* vp = qp + 1024;
  short* yp = y + (size_t)b * Tn * Cn + h * DHn;
  const int lr = lane & 15, lg = lane >> 4;
  const int kr = lane >> 3;            // 0..7 row within 8-row slab
  const int kg = (lane & 7) ^ kr;      // swizzled K source granule

  short8 qf[2][2];
#pragma unroll
  for (int rf = 0; rf < 2; ++rf)
#pragma unroll
    for (int ks = 0; ks < 2; ++ks)
      qf[rf][ks] =
          *(const short8*)(qp + (size_t)(qw + rf * 16 + lr) * SQk + ks * 32 + lg * 8);

  f32x4 o[2][4], mrun[2], lrun[2];
#pragma unroll
  for (int rf = 0; rf < 2; ++rf) {
#pragma unroll
    for (int vf = 0; vf < 4; ++vf) o[rf][vf] = f32x4{0.f, 0.f, 0.f, 0.f};
    mrun[rf] = f32x4{-3e38f, -3e38f, -3e38f, -3e38f};
    lrun[rf] = f32x4{0.f, 0.f, 0.f, 0.f};
  }

  const int ntb = qb * 2 + 2;              // 64-row tiles staged by block
  const int ntw = qb * 2 + 1 + (wave >> 1);  // tiles this wave computes
  short8 vreg[2];

  // prologue: stage tile 0
  gload_lds16(kp + (size_t)(wave * 16 + kr) * SQk + kg * 8, &Kt[0][(wave * 16) * 64]);
  gload_lds16(kp + (size_t)(wave * 16 + 8 + kr) * SQk + kg * 8,
              &Kt[0][(wave * 16 + 8) * 64]);
  vreg[0] = *(const short8*)(vp + (size_t)(wave * 16 + kr) * SQk + (lane & 7) * 8);
  vreg[1] = *(const short8*)(vp + (size_t)(wave * 16 + 8 + kr) * SQk + (lane & 7) * 8);
  asm volatile("s_waitcnt vmcnt(0)" ::: "memory");
#pragma unroll
  for (int l = 0; l < 2; ++l) {
    const int kvl = wave * 16 + l * 8 + kr;
#pragma unroll
    for (int j = 0; j < 8; ++j) Vt[0][((lane & 7) * 8 + j) * 68 + kvl] = vreg[l][j];
  }
  __syncthreads();

  for (int t = 0; t < ntb; ++t) {
    const int bb = t & 1, nx = t + 1;
    if (nx < ntb) {  // issue next-tile loads before compute (2-phase)
      const int nb = nx * 64;
      gload_lds16(kp + (size_t)(nb + wave * 16 + kr) * SQk + kg * 8,
                  &Kt[nx & 1][(wave * 16) * 64]);
      gload_lds16(kp + (size_t)(nb + wave * 16 + 8 + kr) * SQk + kg * 8,
                  &Kt[nx & 1][(wave * 16 + 8) * 64]);
      vreg[0] = *(const short8*)(vp + (size_t)(nb + wave * 16 + kr) * SQk + (lane & 7) * 8);
      vreg[1] =
          *(const short8*)(vp + (size_t)(nb + wave * 16 + 8 + kr) * SQk + (lane & 7) * 8);
    }
    if (t < ntw) {
      const int kbase = t * 64;
      f32x4 s[2][4];
#pragma unroll
      for (int rf = 0; rf < 2; ++rf)
#pragma unroll
        for (int cf = 0; cf < 4; ++cf) s[rf][cf] = f32x4{0.f, 0.f, 0.f, 0.f};
#pragma unroll
      for (int ks = 0; ks < 2; ++ks) {
        short8 kf[4];
#pragma unroll
        for (int cf = 0; cf < 4; ++cf)
          kf[cf] = *(const short8*)&Kt[bb][(cf * 16 + lr) * 64 +
                                           (((ks * 4 + lg) ^ (lr & 7))) * 8];
#pragma unroll
        for (int rf = 0; rf < 2; ++rf)
#pragma unroll
          for (int cf = 0; cf < 4; ++cf)
            s[rf][cf] = __builtin_amdgcn_mfma_f32_16x16x32_bf16(
                qf[rf][ks], kf[cf], s[rf][cf], 0, 0, 0);
      }
      short* Pw = Ps[wave];
#pragma unroll
      for (int rf = 0; rf < 2; ++rf) {
        f32x4 tm;
#pragma unroll
        for (int j = 0; j < 4; ++j) {
          const int qrow = qw + rf * 16 + lg * 4 + j;
          float mx = -3e38f;
#pragma unroll
          for (int cf = 0; cf < 4; ++cf) {
            float sv = s[rf][cf][j] * 0.125f;
            if (kbase + cf * 16 + lr > qrow) sv = -1e30f;
            s[rf][cf][j] = sv;
            mx = fmaxf(mx, sv);
          }
          tm[j] = mx;
        }
#pragma unroll
        for (int mm = 1; mm < 16; mm <<= 1)
#pragma unroll
          for (int j = 0; j < 4; ++j) tm[j] = fmaxf(tm[j], __shfl_xor(tm[j], mm));
        f32x4 mnew, corr, ps;
#pragma unroll
        for (int j = 0; j < 4; ++j) {
          mnew[j] = fmaxf(mrun[rf][j], tm[j]);
          corr[j] = __expf(mrun[rf][j] - mnew[j]);
          mrun[rf][j] = mnew[j];
          ps[j] = 0.f;
        }
#pragma unroll
        for (int cf = 0; cf < 4; ++cf)
#pragma unroll
          for (int j = 0; j < 4; ++j) {
            const float p = __expf(s[rf][cf][j] - mnew[j]);
            ps[j] += p;
            Pw[(rf * 16 + lg * 4 + j) * 68 + cf * 16 + lr] = f2bs(p);
          }
#pragma unroll
        for (int mm = 1; mm < 16; mm <<= 1)
#pragma unroll
          for (int j = 0; j < 4; ++j) ps[j] += __shfl_xor(ps[j], mm);
#pragma unroll
        for (int j = 0; j < 4; ++j) lrun[rf][j] = lrun[rf][j] * corr[j] + ps[j];
#pragma unroll
        for (int vf = 0; vf < 4; ++vf)
#pragma unroll
          for (int j = 0; j < 4; ++j) o[rf][vf][j] *= corr[j];
      }
      // same-wave LDS write->read fence
      asm volatile("s_waitcnt lgkmcnt(0)" ::: "memory");
      __builtin_amdgcn_sched_barrier(0);
      short8 pa[2][2], vb[4][2];
#pragma unroll
      for (int rf = 0; rf < 2; ++rf)
#pragma unroll
        for (int k2 = 0; k2 < 2; ++k2)
          pa[rf][k2] = ld8(&Pw[(rf * 16 + lr) * 68 + k2 * 32 + lg * 8]);
#pragma unroll
      for (int vf = 0; vf < 4; ++vf)
#pragma unroll
        for (int k2 = 0; k2 < 2; ++k2)
          vb[vf][k2] = ld8(&Vt[bb][(vf * 16 + lr) * 68 + k2 * 32 + lg * 8]);
#pragma unroll
      for (int rf = 0; rf < 2; ++rf)
#pragma unroll
        for (int vf = 0; vf < 4; ++vf)
#pragma unroll
          for (int k2 = 0; k2 < 2; ++k2)
            o[rf][vf] = __builtin_amdgcn_mfma_f32_16x16x32_bf16(
                pa[rf][k2], vb[vf][k2], o[rf][vf], 0, 0, 0);
    }
    asm volatile("s_waitcnt vmcnt(0)" ::: "memory");
    if (nx < ntb) {
#pragma unroll
      for (int l = 0; l < 2; ++l) {
        const int kvl = wave * 16 + l * 8 + kr;
#pragma unroll
        for (int j = 0; j < 8; ++j)
          Vt[nx & 1][((lane & 7) * 8 + j) * 68 + kvl] = vreg[l][j];
      }
    }
    __syncthreads();
  }

#pragma unroll
  for (int rf = 0; rf < 2; ++rf) {
    f32x4 inv;
#pragma unroll
    for (int j = 0; j < 4; ++j) inv[j] = 1.0f / lrun[rf][j];
#pragma unroll
    for (int vf = 0; vf < 4; ++vf)
#pragma unroll
      for (int j = 0; j < 4; ++j)
        yp[(size_t)(qw + rf * 16 + lg * 4 + j) * Cn + vf * 16 + lr] =
            f2bs(o[rf][vf][j] * inv[j]);
  }
}

// ---------- launch ----------
extern "C" void kernel_launch(void* const* d_in, const int* in_sizes, int n_in,
                              void* d_out, int out_size, void* d_ws, size_t ws_size,
                              hipStream_t stream) {
  const float* observations = (const float*)d_in[0];
  const float* obs_W = (const float*)d_in[1];
  const float* obs_b = (const float*)d_in[2];
  const float* pos_emb = (const float*)d_in[3];
  const float* ln1_w = (const float*)d_in[4];
  const float* ln1_b = (const float*)d_in[5];
  const float* Wq = (const float*)d_in[6];
  const float* bq = (const float*)d_in[7];
  const float* Wk = (const float*)d_in[8];
  const float* bk = (const float*)d_in[9];
  const float* Wv = (const float*)d_in[10];
  const float* bv = (const float*)d_in[11];
  const float* Wo = (const float*)d_in[12];
  const float* bo = (const float*)d_in[13];
  const float* ln2_w = (const float*)d_in[14];
  const float* ln2_b = (const float*)d_in[15];
  const float* W1 = (const float*)d_in[16];
  const float* b1 = (const float*)d_in[17];
  const float* W2 = (const float*)d_in[18];
  const float* b2 = (const float*)d_in[19];
  const float* lnf_w = (const float*)d_in[20];
  const float* lnf_b = (const float*)d_in[21];
  float* out = (float*)d_out;

  char* ws = (char*)d_ws;
  auto alloc = [&](size_t bytes) -> void* {
    void* p = (void*)ws;
    ws += (bytes + 255) & ~(size_t)255;
    return p;
  };
  const size_t WCC = (size_t)Cn * Cn;        // 262144
  const size_t WCF = (size_t)Cn * 4 * Cn;    // 1048576

  float* xf = (float*)alloc((size_t)Mn * Cn * 4);
  short* hbf = (short*)alloc((size_t)Mn * Cn * 2);
  short* qkvb = (short*)alloc((size_t)Mn * SQk * 2);
  short* ybf = (short*)alloc((size_t)Mn * Cn * 2);
  short* gbf = (short*)alloc((size_t)Mn * 4 * Cn * 2);
  short* obsbf = (short*)alloc((size_t)Mn * ODn * 2);
  short* obsWt = (short*)alloc((size_t)ODn * Cn * 2);
  short* wqkvT = (short*)alloc((size_t)Ln * 3 * WCC * 2);
  short* woT = (short*)alloc((size_t)Ln * WCC * 2);
  short* w1T = (short*)alloc((size_t)Ln * WCF * 2);
  short* w2T = (short*)alloc((size_t)Ln * WCF * 2);
  float* bqkv = (float*)alloc((size_t)Ln * SQk * 4);
  if ((size_t)(ws - (char*)d_ws) > ws_size) return;  // ws too small: bail

  // weight casts/transposes (batched: 4 dispatches) + bias concat
  wtrans4_kernel<<<dim3(16, 16, 24), 256, 0, stream>>>(Wq, Wk, Wv, Wo, wqkvT, woT);
  wtransL_kernel<<<dim3(16, 24, 1), 256, 0, stream>>>(obs_W, obsWt, ODn, Cn);
  wtransL_kernel<<<dim3(64, 16, 6), 256, 0, stream>>>(W1, w1T, Cn, 4 * Cn);
  wtransL_kernel<<<dim3(16, 64, 6), 256, 0, stream>>>(W2, w2T, 4 * Cn, Cn);
  bcat_kernel<<<(Ln * SQk) / 256, 256, 0, stream>>>(bq, bk, bv, bqkv);
  cast_kernel<<<(Mn * ODn) / 256, 256, 0, stream>>>(observations, obsbf);

  // obs embedding: gelu(obs@W+b) + pos -> xf (fp32)
  gemm_kernel<2, 1><<<dim3(Cn / 128, Mn / 128), 256, 0, stream>>>(
      obsbf, obsWt, obs_b, nullptr, xf, pos_emb, ODn, Cn);

  for (int i = 0; i < Ln; ++i) {
    ln_kernel<short><<<Mn, 256, 0, stream>>>(xf, ln1_w + i * Cn, ln1_b + i * Cn, hbf);
    // fused QKV: N = 1536, 3 blocks/CU
    gemm_kernel<0, 1><<<dim3(12, 64), 256, 0, stream>>>(
        hbf, wqkvT + i * 3 * WCC, bqkv + i * SQk, qkvb, nullptr, nullptr, Cn, SQk);
    attn_kernel<<<dim3(Tn / 128, Bn * Hn), 256, 0, stream>>>(qkvb, ybf);
    // Wo: split-K=2, atomic accumulate into residual
    gemm_kernel<3, 2><<<dim3(4, 64, 2), 256, 0, stream>>>(
        ybf, woT + i * WCC, bo + i * Cn, nullptr, xf, nullptr, Cn, Cn);
    ln_kernel<short><<<Mn, 256, 0, stream>>>(xf, ln2_w + i * Cn, ln2_b + i * Cn, hbf);
    gemm_kernel<1, 1><<<dim3(16, 64), 256, 0, stream>>>(
        hbf, w1T + i * WCF, b1 + i * 4 * Cn, gbf, nullptr, nullptr, Cn, 4 * Cn);
    // MLP2: K = 2048, split-K=4
    gemm_kernel<3, 4><<<dim3(4, 64, 4), 256, 0, stream>>>(
        gbf, w2T + i * WCF, b2 + i * Cn, nullptr, xf, nullptr, 4 * Cn, Cn);
  }
  ln_kernel<float><<<Mn, 256, 0, stream>>>(xf, lnf_w, lnf_b, out);
}

// Round 11
// 1472.464 us; speedup vs baseline: 1.3539x; 1.1967x over previous
//
#include <hip/hip_runtime.h>

#define DEVI __device__ __forceinline__

typedef __attribute__((ext_vector_type(8))) short short8;
typedef __attribute__((ext_vector_type(4))) short sh4;
typedef __attribute__((ext_vector_type(4))) float f32x4;

constexpr int Bn = 8, Tn = 1024, Cn = 512, Hn = 8, DHn = 64, Ln = 6, ODn = 768;
constexpr int Mn = Bn * Tn;   // 8192 rows
constexpr int SQk = 1536;     // packed qkv row stride

// ---------- helpers ----------
DEVI short f2bs(float f) {  // fp32 -> bf16 raw bits, round-to-nearest-even
  unsigned u = __builtin_bit_cast(unsigned, f);
  unsigned r = (u + 0x7FFFu + ((u >> 16) & 1u)) >> 16;
  return (short)r;
}

DEVI float gelu_f(float v) {  // exact GELU
  return 0.5f * v * (1.0f + erff(v * 0.70710678118654752f));
}

DEVI void gload_lds16(const void* gp, void* lp) {  // 16B/lane global->LDS DMA
  __builtin_amdgcn_global_load_lds(
      (const __attribute__((address_space(1))) unsigned*)gp,
      (__attribute__((address_space(3))) unsigned*)lp, 16, 0, 0);
}

DEVI short8 ld8(const short* p) {  // 8B-aligned 16-byte LDS read (2 x b64)
  sh4 a = *(const sh4*)p;
  sh4 b = *(const sh4*)(p + 4);
  return __builtin_shufflevector(a, b, 0, 1, 2, 3, 4, 5, 6, 7);
}

// ---------- batched weight cast+transpose fp32 [K,N] -> bf16 [N,K] ----------
__global__ __launch_bounds__(256) void wtrans4_kernel(
    const float* __restrict__ Wq, const float* __restrict__ Wk,
    const float* __restrict__ Wv, const float* __restrict__ Wo,
    short* __restrict__ wqkvT, short* __restrict__ woT) {
  const int z = blockIdx.z, i = z >> 2, which = z & 3;
  const size_t WCC = (size_t)Cn * Cn;
  const float* W = (which == 0) ? Wq : (which == 1) ? Wk : (which == 2) ? Wv : Wo;
  W += (size_t)i * WCC;
  short* dst = (which < 3) ? (wqkvT + (size_t)i * 3 * WCC + (size_t)which * WCC)
                           : (woT + (size_t)i * WCC);
  __shared__ float tile[32][33];
  const int tx = threadIdx.x & 31, ty = threadIdx.x >> 5;
  const int k0 = blockIdx.y * 32, n0 = blockIdx.x * 32;
#pragma unroll
  for (int q = 0; q < 4; ++q)
    tile[ty + q * 8][tx] = W[(size_t)(k0 + ty + q * 8) * Cn + n0 + tx];
  __syncthreads();
#pragma unroll
  for (int q = 0; q < 4; ++q)
    dst[(size_t)(n0 + ty + q * 8) * Cn + k0 + tx] = f2bs(tile[tx][ty + q * 8]);
}

// layered generic transpose (obs_W, W1, W2) — z = layer
__global__ __launch_bounds__(256) void wtransL_kernel(
    const float* __restrict__ W, short* __restrict__ Wt, int K, int N) {
  const int l = blockIdx.z;
  W += (size_t)l * K * N;
  Wt += (size_t)l * K * N;
  __shared__ float tile[32][33];
  const int tx = threadIdx.x & 31, ty = threadIdx.x >> 5;
  const int k0 = blockIdx.y * 32, n0 = blockIdx.x * 32;
#pragma unroll
  for (int q = 0; q < 4; ++q)
    tile[ty + q * 8][tx] = W[(size_t)(k0 + ty + q * 8) * N + n0 + tx];
  __syncthreads();
#pragma unroll
  for (int q = 0; q < 4; ++q)
    Wt[(size_t)(n0 + ty + q * 8) * K + k0 + tx] = f2bs(tile[tx][ty + q * 8]);
}

// concat bq/bk/bv -> bqkv [L][1536]
__global__ __launch_bounds__(256) void bcat_kernel(
    const float* __restrict__ bq, const float* __restrict__ bk,
    const float* __restrict__ bv, float* __restrict__ bqkv) {
  const int i = blockIdx.x * 256 + threadIdx.x;
  const int l = i / 1536, c = i - l * 1536;
  float v = (c < 512) ? bq[l * 512 + c]
                      : (c < 1024) ? bk[l * 512 + c - 512] : bv[l * 512 + c - 1024];
  bqkv[i] = v;
}

// ---------- elementwise fp32 -> bf16 ----------
__global__ __launch_bounds__(256) void cast_kernel(
    const float* __restrict__ in, short* __restrict__ out) {
  const int i = blockIdx.x * 256 + threadIdx.x;
  out[i] = f2bs(in[i]);
}

// ---------- LayerNorm (plain; used only before layer 0) ----------
template <typename OUTT>
__global__ __launch_bounds__(256) void ln_kernel(
    const float* __restrict__ x, const float* __restrict__ w,
    const float* __restrict__ bb, OUTT* __restrict__ out) {
  const int row = blockIdx.x, tid = threadIdx.x;
  const float* xr = x + (size_t)row * Cn;
  const float v0 = xr[tid], v1 = xr[tid + 256];
  float s = v0 + v1, s2 = v0 * v0 + v1 * v1;
#pragma unroll
  for (int m = 1; m < 64; m <<= 1) {
    s += __shfl_xor(s, m);
    s2 += __shfl_xor(s2, m);
  }
  __shared__ float red[8];
  const int wave = tid >> 6, lane = tid & 63;
  if (lane == 0) { red[wave] = s; red[4 + wave] = s2; }
  __syncthreads();
  s = red[0] + red[1] + red[2] + red[3];
  s2 = red[4] + red[5] + red[6] + red[7];
  const float mu = s * (1.0f / Cn);
  const float var = s2 * (1.0f / Cn) - mu * mu;
  const float rstd = rsqrtf(var + 1e-5f);
  const float o0 = (v0 - mu) * rstd * w[tid] + bb[tid];
  const float o1 = (v1 - mu) * rstd * w[tid + 256] + bb[tid + 256];
  if constexpr (sizeof(OUTT) == 2) {
    out[(size_t)row * Cn + tid] = f2bs(o0);
    out[(size_t)row * Cn + tid + 256] = f2bs(o1);
  } else {
    out[(size_t)row * Cn + tid] = o0;
    out[(size_t)row * Cn + tid + 256] = o1;
  }
}

// ---------- fused: x += sum(partials); LayerNorm(x) -> out ----------
template <int NP, typename OUTT, bool WRITEX>
__global__ __launch_bounds__(256) void lnred_kernel(
    float* __restrict__ x, const float* __restrict__ part,
    const float* __restrict__ w, const float* __restrict__ bb,
    OUTT* __restrict__ out) {
  const int row = blockIdx.x, tid = threadIdx.x;
  const size_t base = (size_t)row * Cn;
  float v0 = x[base + tid], v1 = x[base + tid + 256];
#pragma unroll
  for (int p = 0; p < NP; ++p) {
    v0 += part[(size_t)p * Mn * Cn + base + tid];
    v1 += part[(size_t)p * Mn * Cn + base + tid + 256];
  }
  if constexpr (WRITEX) {
    x[base + tid] = v0;
    x[base + tid + 256] = v1;
  }
  float s = v0 + v1, s2 = v0 * v0 + v1 * v1;
#pragma unroll
  for (int m = 1; m < 64; m <<= 1) {
    s += __shfl_xor(s, m);
    s2 += __shfl_xor(s2, m);
  }
  __shared__ float red[8];
  const int wave = tid >> 6, lane = tid & 63;
  if (lane == 0) { red[wave] = s; red[4 + wave] = s2; }
  __syncthreads();
  s = red[0] + red[1] + red[2] + red[3];
  s2 = red[4] + red[5] + red[6] + red[7];
  const float mu = s * (1.0f / Cn);
  const float var = s2 * (1.0f / Cn) - mu * mu;
  const float rstd = rsqrtf(var + 1e-5f);
  const float o0 = (v0 - mu) * rstd * w[tid] + bb[tid];
  const float o1 = (v1 - mu) * rstd * w[tid + 256] + bb[tid + 256];
  if constexpr (sizeof(OUTT) == 2) {
    out[base + tid] = f2bs(o0);
    out[base + tid + 256] = f2bs(o1);
  } else {
    out[base + tid] = o0;
    out[base + tid + 256] = o1;
  }
}

// ---------- bf16 MFMA GEMM: out[M,N] = A[M,K] @ Bt[N,K]^T + bias ----------
// LDS XOR-swizzle: source granule ^= (row&7); read granule ^= (row&7).
// EPI: 0 = bf16 out, 1 = gelu->bf16, 2 = gelu + pos_emb -> fp32 resid,
//      4 = fp32 partial store to resid[z*M*N + idx] (bias on z==0)
template <int EPI, int KS>
__global__ __launch_bounds__(256) void gemm_kernel(
    const short* __restrict__ A, const short* __restrict__ Bt,
    const float* __restrict__ bias, short* __restrict__ outb,
    float* __restrict__ resid, const float* __restrict__ pos, int K, int N) {
  __shared__ __align__(16) short As[128 * 64];
  __shared__ __align__(16) short Bs[128 * 64];
  const int tid = threadIdx.x;
  const int lane = tid & 63;
  const int wave = tid >> 6;
  const int m0 = blockIdx.y * 128;
  const int n0 = blockIdx.x * 128;
  const int z = (KS > 1) ? blockIdx.z : 0;
  const int Ksl = K / KS;
  const int wr = (wave >> 1) * 64;
  const int wc = (wave & 1) * 64;
  const int lA = lane & 15;
  const int lg = lane >> 4;

  f32x4 acc[4][4];
#pragma unroll
  for (int a = 0; a < 4; ++a)
#pragma unroll
    for (int b = 0; b < 4; ++b) acc[a][b] = f32x4{0.f, 0.f, 0.f, 0.f};

  const int rS = tid >> 3;                                // 0..31 staged row
  const int cS = (((tid & 7) ^ ((tid >> 3) & 7))) * 8;    // swizzled src granule
  const short* Ag = A + (size_t)(m0 + rS) * K + cS;
  const short* Bg = Bt + (size_t)(n0 + rS) * K + cS;

  for (int kk = z * Ksl; kk < z * Ksl + Ksl; kk += 64) {
#pragma unroll
    for (int it = 0; it < 4; ++it) {
      gload_lds16(Ag + (size_t)it * 32 * K + kk, &As[it * 2048 + wave * 512]);
      gload_lds16(Bg + (size_t)it * 32 * K + kk, &Bs[it * 2048 + wave * 512]);
    }
    __syncthreads();
#pragma unroll
    for (int ks = 0; ks < 2; ++ks) {
      const int gA = ((ks * 4 + lg) ^ (lA & 7)) * 8;  // swizzled read granule
      short8 af[4], bf[4];
#pragma unroll
      for (int i = 0; i < 4; ++i) {
        af[i] = *(const short8*)&As[(wr + i * 16 + lA) * 64 + gA];
        bf[i] = *(const short8*)&Bs[(wc + i * 16 + lA) * 64 + gA];
      }
#pragma unroll
      for (int mi = 0; mi < 4; ++mi)
#pragma unroll
        for (int ni = 0; ni < 4; ++ni)
          acc[mi][ni] = __builtin_amdgcn_mfma_f32_16x16x32_bf16(
              af[mi], bf[ni], acc[mi][ni], 0, 0, 0);
    }
    __syncthreads();
  }

#pragma unroll
  for (int mi = 0; mi < 4; ++mi) {
    const int row = m0 + wr + mi * 16 + (lane >> 4) * 4;
#pragma unroll
    for (int ni = 0; ni < 4; ++ni) {
      const int col = n0 + wc + ni * 16 + (lane & 15);
      const float bv = (KS == 1 || z == 0) ? bias[col] : 0.f;
#pragma unroll
      for (int j = 0; j < 4; ++j) {
        const float v = acc[mi][ni][j] + bv;
        const size_t idx = (size_t)(row + j) * N + col;
        if constexpr (EPI == 0) {
          outb[idx] = f2bs(v);
        } else if constexpr (EPI == 1) {
          outb[idx] = f2bs(gelu_f(v));
        } else if constexpr (EPI == 2) {
          resid[idx] = gelu_f(v) + pos[(size_t)((row + j) & (Tn - 1)) * Cn + col];
        } else {  // EPI == 4: partial store
          resid[(size_t)z * Mn * N + idx] = v;
        }
      }
    }
  }
}

// ---------- causal flash attention ----------
__global__ __launch_bounds__(256) void attn_kernel(
    const short* __restrict__ qkv, short* __restrict__ y) {
  __shared__ __align__(16) short Kt[2][64 * 64];   // linear, swizzled granules
  __shared__ __align__(16) short Vt[2][64 * 68];   // [d][kv] pad->68
  __shared__ __align__(16) short Ps[4][32 * 68];   // per-wave P, pad->68
  const int tid = threadIdx.x, lane = tid & 63, wave = tid >> 6;
  const int qb = blockIdx.x;
  const int bh = blockIdx.y;
  const int b = bh >> 3, h = bh & 7;
  const int qw = qb * 128 + wave * 32;
  const short* qp = qkv + (size_t)b * Tn * SQk + h * DHn;
  const short* kp = qp + 512;
  const short* vp = qp + 1024;
  short* yp = y + (size_t)b * Tn * Cn + h * DHn;
  const int lr = lane & 15, lg = lane >> 4;
  const int kr = lane >> 3;            // 0..7 row within 8-row slab
  const int kg = (lane & 7) ^ kr;      // swizzled K source granule

  short8 qf[2][2];
#pragma unroll
  for (int rf = 0; rf < 2; ++rf)
#pragma unroll
    for (int ks = 0; ks < 2; ++ks)
      qf[rf][ks] =
          *(const short8*)(qp + (size_t)(qw + rf * 16 + lr) * SQk + ks * 32 + lg * 8);

  f32x4 o[2][4], mrun[2], lrun[2];
#pragma unroll
  for (int rf = 0; rf < 2; ++rf) {
#pragma unroll
    for (int vf = 0; vf < 4; ++vf) o[rf][vf] = f32x4{0.f, 0.f, 0.f, 0.f};
    mrun[rf] = f32x4{-3e38f, -3e38f, -3e38f, -3e38f};
    lrun[rf] = f32x4{0.f, 0.f, 0.f, 0.f};
  }

  const int ntb = qb * 2 + 2;                // 64-row tiles staged by block
  const int ntw = qb * 2 + 1 + (wave >> 1);  // tiles this wave computes
  short8 vreg[2];

  // prologue: stage tile 0
  gload_lds16(kp + (size_t)(wave * 16 + kr) * SQk + kg * 8, &Kt[0][(wave * 16) * 64]);
  gload_lds16(kp + (size_t)(wave * 16 + 8 + kr) * SQk + kg * 8,
              &Kt[0][(wave * 16 + 8) * 64]);
  vreg[0] = *(const short8*)(vp + (size_t)(wave * 16 + kr) * SQk + (lane & 7) * 8);
  vreg[1] = *(const short8*)(vp + (size_t)(wave * 16 + 8 + kr) * SQk + (lane & 7) * 8);
  asm volatile("s_waitcnt vmcnt(0)" ::: "memory");
#pragma unroll
  for (int l = 0; l < 2; ++l) {
    const int kvl = wave * 16 + l * 8 + kr;
#pragma unroll
    for (int j = 0; j < 8; ++j) Vt[0][((lane & 7) * 8 + j) * 68 + kvl] = vreg[l][j];
  }
  __syncthreads();

  for (int t = 0; t < ntb; ++t) {
    const int bb = t & 1, nx = t + 1;
    if (nx < ntb) {  // issue next-tile loads before compute (2-phase)
      const int nb = nx * 64;
      gload_lds16(kp + (size_t)(nb + wave * 16 + kr) * SQk + kg * 8,
                  &Kt[nx & 1][(wave * 16) * 64]);
      gload_lds16(kp + (size_t)(nb + wave * 16 + 8 + kr) * SQk + kg * 8,
                  &Kt[nx & 1][(wave * 16 + 8) * 64]);
      vreg[0] = *(const short8*)(vp + (size_t)(nb + wave * 16 + kr) * SQk + (lane & 7) * 8);
      vreg[1] =
          *(const short8*)(vp + (size_t)(nb + wave * 16 + 8 + kr) * SQk + (lane & 7) * 8);
    }
    if (t < ntw) {
      const int kbase = t * 64;
      f32x4 s[2][4];
#pragma unroll
      for (int rf = 0; rf < 2; ++rf)
#pragma unroll
        for (int cf = 0; cf < 4; ++cf) s[rf][cf] = f32x4{0.f, 0.f, 0.f, 0.f};
#pragma unroll
      for (int ks = 0; ks < 2; ++ks) {
        short8 kf[4];
#pragma unroll
        for (int cf = 0; cf < 4; ++cf)
          kf[cf] = *(const short8*)&Kt[bb][(cf * 16 + lr) * 64 +
                                           (((ks * 4 + lg) ^ (lr & 7))) * 8];
#pragma unroll
        for (int rf = 0; rf < 2; ++rf)
#pragma unroll
          for (int cf = 0; cf < 4; ++cf)
            s[rf][cf] = __builtin_amdgcn_mfma_f32_16x16x32_bf16(
                qf[rf][ks], kf[cf], s[rf][cf], 0, 0, 0);
      }
      short* Pw = Ps[wave];
#pragma unroll
      for (int rf = 0; rf < 2; ++rf) {
        f32x4 tm;
#pragma unroll
        for (int j = 0; j < 4; ++j) {
          const int qrow = qw + rf * 16 + lg * 4 + j;
          float mx = -3e38f;
#pragma unroll
          for (int cf = 0; cf < 4; ++cf) {
            float sv = s[rf][cf][j] * 0.125f;
            if (kbase + cf * 16 + lr > qrow) sv = -1e30f;
            s[rf][cf][j] = sv;
            mx = fmaxf(mx, sv);
          }
          tm[j] = mx;
        }
#pragma unroll
        for (int mm = 1; mm < 16; mm <<= 1)
#pragma unroll
          for (int j = 0; j < 4; ++j) tm[j] = fmaxf(tm[j], __shfl_xor(tm[j], mm));
        f32x4 mnew, corr, ps;
#pragma unroll
        for (int j = 0; j < 4; ++j) {
          mnew[j] = fmaxf(mrun[rf][j], tm[j]);
          corr[j] = __expf(mrun[rf][j] - mnew[j]);
          mrun[rf][j] = mnew[j];
          ps[j] = 0.f;
        }
#pragma unroll
        for (int cf = 0; cf < 4; ++cf)
#pragma unroll
          for (int j = 0; j < 4; ++j) {
            const float p = __expf(s[rf][cf][j] - mnew[j]);
            ps[j] += p;
            Pw[(rf * 16 + lg * 4 + j) * 68 + cf * 16 + lr] = f2bs(p);
          }
#pragma unroll
        for (int mm = 1; mm < 16; mm <<= 1)
#pragma unroll
          for (int j = 0; j < 4; ++j) ps[j] += __shfl_xor(ps[j], mm);
#pragma unroll
        for (int j = 0; j < 4; ++j) lrun[rf][j] = lrun[rf][j] * corr[j] + ps[j];
#pragma unroll
        for (int vf = 0; vf < 4; ++vf)
#pragma unroll
          for (int j = 0; j < 4; ++j) o[rf][vf][j] *= corr[j];
      }
      // same-wave LDS write->read fence
      asm volatile("s_waitcnt lgkmcnt(0)" ::: "memory");
      __builtin_amdgcn_sched_barrier(0);
      short8 pa[2][2], vb[4][2];
#pragma unroll
      for (int rf = 0; rf < 2; ++rf)
#pragma unroll
        for (int k2 = 0; k2 < 2; ++k2)
          pa[rf][k2] = ld8(&Pw[(rf * 16 + lr) * 68 + k2 * 32 + lg * 8]);
#pragma unroll
      for (int vf = 0; vf < 4; ++vf)
#pragma unroll
        for (int k2 = 0; k2 < 2; ++k2)
          vb[vf][k2] = ld8(&Vt[bb][(vf * 16 + lr) * 68 + k2 * 32 + lg * 8]);
#pragma unroll
      for (int rf = 0; rf < 2; ++rf)
#pragma unroll
        for (int vf = 0; vf < 4; ++vf)
#pragma unroll
          for (int k2 = 0; k2 < 2; ++k2)
            o[rf][vf] = __builtin_amdgcn_mfma_f32_16x16x32_bf16(
                pa[rf][k2], vb[vf][k2], o[rf][vf], 0, 0, 0);
    }
    asm volatile("s_waitcnt vmcnt(0)" ::: "memory");
    if (nx < ntb) {
#pragma unroll
      for (int l = 0; l < 2; ++l) {
        const int kvl = wave * 16 + l * 8 + kr;
#pragma unroll
        for (int j = 0; j < 8; ++j)
          Vt[nx & 1][((lane & 7) * 8 + j) * 68 + kvl] = vreg[l][j];
      }
    }
    __syncthreads();
  }

#pragma unroll
  for (int rf = 0; rf < 2; ++rf) {
    f32x4 inv;
#pragma unroll
    for (int j = 0; j < 4; ++j) inv[j] = 1.0f / lrun[rf][j];
#pragma unroll
    for (int vf = 0; vf < 4; ++vf)
#pragma unroll
      for (int j = 0; j < 4; ++j)
        yp[(size_t)(qw + rf * 16 + lg * 4 + j) * Cn + vf * 16 + lr] =
            f2bs(o[rf][vf][j] * inv[j]);
  }
}

// ---------- launch ----------
extern "C" void kernel_launch(void* const* d_in, const int* in_sizes, int n_in,
                              void* d_out, int out_size, void* d_ws, size_t ws_size,
                              hipStream_t stream) {
  const float* observations = (const float*)d_in[0];
  const float* obs_W = (const float*)d_in[1];
  const float* obs_b = (const float*)d_in[2];
  const float* pos_emb = (const float*)d_in[3];
  const float* ln1_w = (const float*)d_in[4];
  const float* ln1_b = (const float*)d_in[5];
  const float* Wq = (const float*)d_in[6];
  const float* bq = (const float*)d_in[7];
  const float* Wk = (const float*)d_in[8];
  const float* bk = (const float*)d_in[9];
  const float* Wv = (const float*)d_in[10];
  const float* bv = (const float*)d_in[11];
  const float* Wo = (const float*)d_in[12];
  const float* bo = (const float*)d_in[13];
  const float* ln2_w = (const float*)d_in[14];
  const float* ln2_b = (const float*)d_in[15];
  const float* W1 = (const float*)d_in[16];
  const float* b1 = (const float*)d_in[17];
  const float* W2 = (const float*)d_in[18];
  const float* b2 = (const float*)d_in[19];
  const float* lnf_w = (const float*)d_in[20];
  const float* lnf_b = (const float*)d_in[21];
  float* out = (float*)d_out;

  char* ws = (char*)d_ws;
  auto alloc = [&](size_t bytes) -> void* {
    void* p = (void*)ws;
    ws += (bytes + 255) & ~(size_t)255;
    return p;
  };
  const size_t WCC = (size_t)Cn * Cn;        // 262144
  const size_t WCF = (size_t)Cn * 4 * Cn;    // 1048576

  float* xf = (float*)alloc((size_t)Mn * Cn * 4);
  short* hbf = (short*)alloc((size_t)Mn * Cn * 2);
  short* qkvb = (short*)alloc((size_t)Mn * SQk * 2);
  short* ybf = (short*)alloc((size_t)Mn * Cn * 2);
  short* gbf = (short*)alloc((size_t)Mn * 4 * Cn * 2);   // also aliases partWo
  float* partM = (float*)alloc((size_t)2 * Mn * Cn * 4); // MLP2 partials
  short* obsbf = (short*)alloc((size_t)Mn * ODn * 2);
  short* obsWt = (short*)alloc((size_t)ODn * Cn * 2);
  short* wqkvT = (short*)alloc((size_t)Ln * 3 * WCC * 2);
  short* woT = (short*)alloc((size_t)Ln * WCC * 2);
  short* w1T = (short*)alloc((size_t)Ln * WCF * 2);
  short* w2T = (short*)alloc((size_t)Ln * WCF * 2);
  float* bqkv = (float*)alloc((size_t)Ln * SQk * 4);
  if ((size_t)(ws - (char*)d_ws) > ws_size) return;  // ws too small: bail
  float* partWo = (float*)gbf;  // lifetimes disjoint: [Wo, lnred2] vs [MLP1, MLP2]

  // weight casts/transposes (batched) + bias concat
  wtrans4_kernel<<<dim3(16, 16, 24), 256, 0, stream>>>(Wq, Wk, Wv, Wo, wqkvT, woT);
  wtransL_kernel<<<dim3(16, 24, 1), 256, 0, stream>>>(obs_W, obsWt, ODn, Cn);
  wtransL_kernel<<<dim3(64, 16, 6), 256, 0, stream>>>(W1, w1T, Cn, 4 * Cn);
  wtransL_kernel<<<dim3(16, 64, 6), 256, 0, stream>>>(W2, w2T, 4 * Cn, Cn);
  bcat_kernel<<<(Ln * SQk) / 256, 256, 0, stream>>>(bq, bk, bv, bqkv);
  cast_kernel<<<(Mn * ODn) / 256, 256, 0, stream>>>(observations, obsbf);

  // obs embedding: gelu(obs@W+b) + pos -> xf (fp32)
  gemm_kernel<2, 1><<<dim3(Cn / 128, Mn / 128), 256, 0, stream>>>(
      obsbf, obsWt, obs_b, nullptr, xf, pos_emb, ODn, Cn);

  // layer 0 ln1 (no partials yet)
  ln_kernel<short><<<Mn, 256, 0, stream>>>(xf, ln1_w, ln1_b, hbf);

  for (int i = 0; i < Ln; ++i) {
    // fused QKV: N = 1536
    gemm_kernel<0, 1><<<dim3(12, 64), 256, 0, stream>>>(
        hbf, wqkvT + i * 3 * WCC, bqkv + i * SQk, qkvb, nullptr, nullptr, Cn, SQk);
    attn_kernel<<<dim3(Tn / 128, Bn * Hn), 256, 0, stream>>>(qkvb, ybf);
    // Wo: split-K=2 -> fp32 partials (no atomics)
    gemm_kernel<4, 2><<<dim3(4, 64, 2), 256, 0, stream>>>(
        ybf, woT + i * WCC, bo + i * Cn, nullptr, partWo, nullptr, Cn, Cn);
    // ln2 fused with partial reduction; updates xf
    lnred_kernel<2, short, true><<<Mn, 256, 0, stream>>>(
        xf, partWo, ln2_w + i * Cn, ln2_b + i * Cn, hbf);
    gemm_kernel<1, 1><<<dim3(16, 64), 256, 0, stream>>>(
        hbf, w1T + i * WCF, b1 + i * 4 * Cn, gbf, nullptr, nullptr, Cn, 4 * Cn);
    // MLP2: K = 2048, split-K=2 -> fp32 partials
    gemm_kernel<4, 2><<<dim3(4, 64, 2), 256, 0, stream>>>(
        gbf, w2T + i * WCF, b2 + i * Cn, nullptr, partM, nullptr, 4 * Cn, Cn);
    if (i < Ln - 1) {
      // next layer's ln1 fused with MLP2 partial reduction; updates xf
      lnred_kernel<2, short, true><<<Mn, 256, 0, stream>>>(
          xf, partM, ln1_w + (i + 1) * Cn, ln1_b + (i + 1) * Cn, hbf);
    } else {
      // final LN fused with last MLP2 partial reduction -> fp32 out
      lnred_kernel<2, float, false><<<Mn, 256, 0, stream>>>(
          xf, partM, lnf_w, lnf_b, out);
    }
  }
}

// Round 12
// 1368.729 us; speedup vs baseline: 1.4565x; 1.0758x over previous
//
#include <hip/hip_runtime.h>

#define DEVI __device__ __forceinline__

typedef __attribute__((ext_vector_type(8))) short short8;
typedef __attribute__((ext_vector_type(4))) short sh4;
typedef __attribute__((ext_vector_type(4))) float f32x4;

constexpr int Bn = 8, Tn = 1024, Cn = 512, Hn = 8, DHn = 64, Ln = 6, ODn = 768;
constexpr int Mn = Bn * Tn;   // 8192 rows
constexpr int SQk = 1536;     // packed qkv row stride

// ---------- helpers ----------
DEVI short f2bs(float f) {  // fp32 -> bf16 raw bits, round-to-nearest-even
  unsigned u = __builtin_bit_cast(unsigned, f);
  unsigned r = (u + 0x7FFFu + ((u >> 16) & 1u)) >> 16;
  return (short)r;
}

DEVI float gelu_f(float v) {  // exact GELU
  return 0.5f * v * (1.0f + erff(v * 0.70710678118654752f));
}

DEVI void gload_lds16(const void* gp, void* lp) {  // 16B/lane global->LDS DMA
  __builtin_amdgcn_global_load_lds(
      (const __attribute__((address_space(1))) unsigned*)gp,
      (__attribute__((address_space(3))) unsigned*)lp, 16, 0, 0);
}

DEVI short8 ld8(const short* p) {  // 8B-aligned 16-byte LDS read (2 x b64)
  sh4 a = *(const sh4*)p;
  sh4 b = *(const sh4*)(p + 4);
  return __builtin_shufflevector(a, b, 0, 1, 2, 3, 4, 5, 6, 7);
}

// ---------- batched weight cast+transpose fp32 [K,N] -> bf16 [N,K] ----------
__global__ __launch_bounds__(256) void wtrans4_kernel(
    const float* __restrict__ Wq, const float* __restrict__ Wk,
    const float* __restrict__ Wv, const float* __restrict__ Wo,
    short* __restrict__ wqkvT, short* __restrict__ woT) {
  const int z = blockIdx.z, i = z >> 2, which = z & 3;
  const size_t WCC = (size_t)Cn * Cn;
  const float* W = (which == 0) ? Wq : (which == 1) ? Wk : (which == 2) ? Wv : Wo;
  W += (size_t)i * WCC;
  short* dst = (which < 3) ? (wqkvT + (size_t)i * 3 * WCC + (size_t)which * WCC)
                           : (woT + (size_t)i * WCC);
  __shared__ float tile[32][33];
  const int tx = threadIdx.x & 31, ty = threadIdx.x >> 5;
  const int k0 = blockIdx.y * 32, n0 = blockIdx.x * 32;
#pragma unroll
  for (int q = 0; q < 4; ++q)
    tile[ty + q * 8][tx] = W[(size_t)(k0 + ty + q * 8) * Cn + n0 + tx];
  __syncthreads();
#pragma unroll
  for (int q = 0; q < 4; ++q)
    dst[(size_t)(n0 + ty + q * 8) * Cn + k0 + tx] = f2bs(tile[tx][ty + q * 8]);
}

// layered generic transpose (obs_W, W1, W2) — z = layer
__global__ __launch_bounds__(256) void wtransL_kernel(
    const float* __restrict__ W, short* __restrict__ Wt, int K, int N) {
  const int l = blockIdx.z;
  W += (size_t)l * K * N;
  Wt += (size_t)l * K * N;
  __shared__ float tile[32][33];
  const int tx = threadIdx.x & 31, ty = threadIdx.x >> 5;
  const int k0 = blockIdx.y * 32, n0 = blockIdx.x * 32;
#pragma unroll
  for (int q = 0; q < 4; ++q)
    tile[ty + q * 8][tx] = W[(size_t)(k0 + ty + q * 8) * N + n0 + tx];
  __syncthreads();
#pragma unroll
  for (int q = 0; q < 4; ++q)
    Wt[(size_t)(n0 + ty + q * 8) * K + k0 + tx] = f2bs(tile[tx][ty + q * 8]);
}

// concat bq/bk/bv -> bqkv [L][1536]
__global__ __launch_bounds__(256) void bcat_kernel(
    const float* __restrict__ bq, const float* __restrict__ bk,
    const float* __restrict__ bv, float* __restrict__ bqkv) {
  const int i = blockIdx.x * 256 + threadIdx.x;
  const int l = i / 1536, c = i - l * 1536;
  float v = (c < 512) ? bq[l * 512 + c]
                      : (c < 1024) ? bk[l * 512 + c - 512] : bv[l * 512 + c - 1024];
  bqkv[i] = v;
}

// ---------- elementwise fp32 -> bf16 (vectorized x4) ----------
__global__ __launch_bounds__(256) void cast_kernel(
    const float4* __restrict__ in, sh4* __restrict__ out) {
  const int i = blockIdx.x * 256 + threadIdx.x;
  const float4 v = in[i];
  sh4 o;
  o[0] = f2bs(v.x); o[1] = f2bs(v.y); o[2] = f2bs(v.z); o[3] = f2bs(v.w);
  out[i] = o;
}

// ---------- LayerNorm (plain; used only before layer 0) ----------
template <typename OUTT>
__global__ __launch_bounds__(256) void ln_kernel(
    const float* __restrict__ x, const float* __restrict__ w,
    const float* __restrict__ bb, OUTT* __restrict__ out) {
  const int row = blockIdx.x, tid = threadIdx.x;
  const float* xr = x + (size_t)row * Cn;
  const float v0 = xr[tid], v1 = xr[tid + 256];
  float s = v0 + v1, s2 = v0 * v0 + v1 * v1;
#pragma unroll
  for (int m = 1; m < 64; m <<= 1) {
    s += __shfl_xor(s, m);
    s2 += __shfl_xor(s2, m);
  }
  __shared__ float red[8];
  const int wave = tid >> 6, lane = tid & 63;
  if (lane == 0) { red[wave] = s; red[4 + wave] = s2; }
  __syncthreads();
  s = red[0] + red[1] + red[2] + red[3];
  s2 = red[4] + red[5] + red[6] + red[7];
  const float mu = s * (1.0f / Cn);
  const float var = s2 * (1.0f / Cn) - mu * mu;
  const float rstd = rsqrtf(var + 1e-5f);
  const float o0 = (v0 - mu) * rstd * w[tid] + bb[tid];
  const float o1 = (v1 - mu) * rstd * w[tid + 256] + bb[tid + 256];
  if constexpr (sizeof(OUTT) == 2) {
    out[(size_t)row * Cn + tid] = f2bs(o0);
    out[(size_t)row * Cn + tid + 256] = f2bs(o1);
  } else {
    out[(size_t)row * Cn + tid] = o0;
    out[(size_t)row * Cn + tid + 256] = o1;
  }
}

// ---------- fused: x += sum(partials); LayerNorm(x) -> out ----------
template <int NP, typename OUTT, bool WRITEX>
__global__ __launch_bounds__(256) void lnred_kernel(
    float* __restrict__ x, const float* __restrict__ part,
    const float* __restrict__ w, const float* __restrict__ bb,
    OUTT* __restrict__ out) {
  const int row = blockIdx.x, tid = threadIdx.x;
  const size_t base = (size_t)row * Cn;
  float v0 = x[base + tid], v1 = x[base + tid + 256];
#pragma unroll
  for (int p = 0; p < NP; ++p) {
    v0 += part[(size_t)p * Mn * Cn + base + tid];
    v1 += part[(size_t)p * Mn * Cn + base + tid + 256];
  }
  if constexpr (WRITEX) {
    x[base + tid] = v0;
    x[base + tid + 256] = v1;
  }
  float s = v0 + v1, s2 = v0 * v0 + v1 * v1;
#pragma unroll
  for (int m = 1; m < 64; m <<= 1) {
    s += __shfl_xor(s, m);
    s2 += __shfl_xor(s2, m);
  }
  __shared__ float red[8];
  const int wave = tid >> 6, lane = tid & 63;
  if (lane == 0) { red[wave] = s; red[4 + wave] = s2; }
  __syncthreads();
  s = red[0] + red[1] + red[2] + red[3];
  s2 = red[4] + red[5] + red[6] + red[7];
  const float mu = s * (1.0f / Cn);
  const float var = s2 * (1.0f / Cn) - mu * mu;
  const float rstd = rsqrtf(var + 1e-5f);
  const float o0 = (v0 - mu) * rstd * w[tid] + bb[tid];
  const float o1 = (v1 - mu) * rstd * w[tid + 256] + bb[tid + 256];
  if constexpr (sizeof(OUTT) == 2) {
    out[base + tid] = f2bs(o0);
    out[base + tid + 256] = f2bs(o1);
  } else {
    out[base + tid] = o0;
    out[base + tid + 256] = o1;
  }
}

// ---------- bf16 MFMA GEMM: out[M,N] = A[M,K] @ Bt[N,K]^T + bias ----------
// LDS XOR-swizzle: source granule ^= (row&7); read granule ^= (row&7).
// EPI: 0 = bf16 out, 1 = gelu->bf16, 2 = gelu + pos_emb -> fp32 resid,
//      4 = fp32 partial store to resid[z*M*N + idx] (bias on z==0)
template <int EPI, int KS>
__global__ __launch_bounds__(256) void gemm_kernel(
    const short* __restrict__ A, const short* __restrict__ Bt,
    const float* __restrict__ bias, short* __restrict__ outb,
    float* __restrict__ resid, const float* __restrict__ pos, int K, int N) {
  __shared__ __align__(16) short As[128 * 64];
  __shared__ __align__(16) short Bs[128 * 64];
  const int tid = threadIdx.x;
  const int lane = tid & 63;
  const int wave = tid >> 6;
  const int m0 = blockIdx.y * 128;
  const int n0 = blockIdx.x * 128;
  const int z = (KS > 1) ? blockIdx.z : 0;
  const int Ksl = K / KS;
  const int wr = (wave >> 1) * 64;
  const int wc = (wave & 1) * 64;
  const int lA = lane & 15;
  const int lg = lane >> 4;

  f32x4 acc[4][4];
#pragma unroll
  for (int a = 0; a < 4; ++a)
#pragma unroll
    for (int b = 0; b < 4; ++b) acc[a][b] = f32x4{0.f, 0.f, 0.f, 0.f};

  const int rS = tid >> 3;                                // 0..31 staged row
  const int cS = (((tid & 7) ^ ((tid >> 3) & 7))) * 8;    // swizzled src granule
  const short* Ag = A + (size_t)(m0 + rS) * K + cS;
  const short* Bg = Bt + (size_t)(n0 + rS) * K + cS;

  for (int kk = z * Ksl; kk < z * Ksl + Ksl; kk += 64) {
#pragma unroll
    for (int it = 0; it < 4; ++it) {
      gload_lds16(Ag + (size_t)it * 32 * K + kk, &As[it * 2048 + wave * 512]);
      gload_lds16(Bg + (size_t)it * 32 * K + kk, &Bs[it * 2048 + wave * 512]);
    }
    __syncthreads();
#pragma unroll
    for (int ks = 0; ks < 2; ++ks) {
      const int gA = ((ks * 4 + lg) ^ (lA & 7)) * 8;  // swizzled read granule
      short8 af[4], bf[4];
#pragma unroll
      for (int i = 0; i < 4; ++i) {
        af[i] = *(const short8*)&As[(wr + i * 16 + lA) * 64 + gA];
        bf[i] = *(const short8*)&Bs[(wc + i * 16 + lA) * 64 + gA];
      }
#pragma unroll
      for (int mi = 0; mi < 4; ++mi)
#pragma unroll
        for (int ni = 0; ni < 4; ++ni)
          acc[mi][ni] = __builtin_amdgcn_mfma_f32_16x16x32_bf16(
              af[mi], bf[ni], acc[mi][ni], 0, 0, 0);
    }
    __syncthreads();
  }

#pragma unroll
  for (int mi = 0; mi < 4; ++mi) {
    const int row = m0 + wr + mi * 16 + (lane >> 4) * 4;
#pragma unroll
    for (int ni = 0; ni < 4; ++ni) {
      const int col = n0 + wc + ni * 16 + (lane & 15);
      const float bv = (KS == 1 || z == 0) ? bias[col] : 0.f;
#pragma unroll
      for (int j = 0; j < 4; ++j) {
        const float v = acc[mi][ni][j] + bv;
        const size_t idx = (size_t)(row + j) * N + col;
        if constexpr (EPI == 0) {
          outb[idx] = f2bs(v);
        } else if constexpr (EPI == 1) {
          outb[idx] = f2bs(gelu_f(v));
        } else if constexpr (EPI == 2) {
          resid[idx] = gelu_f(v) + pos[(size_t)((row + j) & (Tn - 1)) * Cn + col];
        } else {  // EPI == 4: partial store
          resid[(size_t)z * Mn * N + idx] = v;
        }
      }
    }
  }
}

// ---------- causal flash attention (paired diagonal q-tiles, 8 waves) ----------
// grid: (4, B*H); block 512. Waves 0-3 own q-tile qbp, waves 4-7 own 7-qbp;
// per-block work is uniform (9 units). Shared K/V staging to the pair max.
__global__ __launch_bounds__(512) void attn_kernel(
    const short* __restrict__ qkv, short* __restrict__ y) {
  __shared__ __align__(16) short Kt[2][64 * 64];   // linear, swizzled granules
  __shared__ __align__(16) short Vt[2][64 * 68];   // [d][kv] pad->68
  __shared__ __align__(16) short Ps[8][32 * 68];   // per-wave P, pad->68
  const int tid = threadIdx.x, lane = tid & 63, wave = tid >> 6;  // 0..7
  const int qbp = blockIdx.x;              // 0..3 pair id
  const int bh = blockIdx.y;
  const int b = bh >> 3, h = bh & 7;
  const int qtile = (wave < 4) ? qbp : (7 - qbp);
  const int w4 = wave & 3;
  const int qw = qtile * 128 + w4 * 32;
  const short* qp = qkv + (size_t)b * Tn * SQk + h * DHn;
  const short* kp = qp + 512;
  const short* vp = qp + 1024;
  short* yp = y + (size_t)b * Tn * Cn + h * DHn;
  const int lr = lane & 15, lg = lane >> 4;
  const int kr = lane >> 3;            // 0..7 row within 8-row slab
  const int kg = (lane & 7) ^ kr;      // swizzled K source granule

  short8 qf[2][2];
#pragma unroll
  for (int rf = 0; rf < 2; ++rf)
#pragma unroll
    for (int ks = 0; ks < 2; ++ks)
      qf[rf][ks] =
          *(const short8*)(qp + (size_t)(qw + rf * 16 + lr) * SQk + ks * 32 + lg * 8);

  f32x4 o[2][4], mrun[2], lrun[2];
#pragma unroll
  for (int rf = 0; rf < 2; ++rf) {
#pragma unroll
    for (int vf = 0; vf < 4; ++vf) o[rf][vf] = f32x4{0.f, 0.f, 0.f, 0.f};
    mrun[rf] = f32x4{-3e38f, -3e38f, -3e38f, -3e38f};
    lrun[rf] = f32x4{0.f, 0.f, 0.f, 0.f};
  }

  const int ntb = (7 - qbp) * 2 + 2;         // tiles staged (pair max)
  const int ntw = qtile * 2 + 1 + (w4 >> 1); // tiles this wave computes
  short8 vreg;

  // prologue: stage tile 0 (each wave: 8 K rows via DMA + 8 V rows via reg)
  gload_lds16(kp + (size_t)(wave * 8 + kr) * SQk + kg * 8, &Kt[0][(wave * 8) * 64]);
  vreg = *(const short8*)(vp + (size_t)(wave * 8 + kr) * SQk + (lane & 7) * 8);
  asm volatile("s_waitcnt vmcnt(0)" ::: "memory");
  {
    const int kvl = wave * 8 + kr;
#pragma unroll
    for (int j = 0; j < 8; ++j) Vt[0][((lane & 7) * 8 + j) * 68 + kvl] = vreg[j];
  }
  __syncthreads();

  for (int t = 0; t < ntb; ++t) {
    const int bb = t & 1, nx = t + 1;
    if (nx < ntb) {  // issue next-tile loads before compute (2-phase)
      const int nb = nx * 64;
      gload_lds16(kp + (size_t)(nb + wave * 8 + kr) * SQk + kg * 8,
                  &Kt[nx & 1][(wave * 8) * 64]);
      vreg = *(const short8*)(vp + (size_t)(nb + wave * 8 + kr) * SQk + (lane & 7) * 8);
    }
    if (t < ntw) {
      const int kbase = t * 64;
      f32x4 s[2][4];
#pragma unroll
      for (int rf = 0; rf < 2; ++rf)
#pragma unroll
        for (int cf = 0; cf < 4; ++cf) s[rf][cf] = f32x4{0.f, 0.f, 0.f, 0.f};
#pragma unroll
      for (int ks = 0; ks < 2; ++ks) {
        short8 kf[4];
#pragma unroll
        for (int cf = 0; cf < 4; ++cf)
          kf[cf] = *(const short8*)&Kt[bb][(cf * 16 + lr) * 64 +
                                           (((ks * 4 + lg) ^ (lr & 7))) * 8];
#pragma unroll
        for (int rf = 0; rf < 2; ++rf)
#pragma unroll
          for (int cf = 0; cf < 4; ++cf)
            s[rf][cf] = __builtin_amdgcn_mfma_f32_16x16x32_bf16(
                qf[rf][ks], kf[cf], s[rf][cf], 0, 0, 0);
      }
      short* Pw = Ps[wave];
#pragma unroll
      for (int rf = 0; rf < 2; ++rf) {
        f32x4 tm;
#pragma unroll
        for (int j = 0; j < 4; ++j) {
          const int qrow = qw + rf * 16 + lg * 4 + j;
          float mx = -3e38f;
#pragma unroll
          for (int cf = 0; cf < 4; ++cf) {
            float sv = s[rf][cf][j] * 0.125f;
            if (kbase + cf * 16 + lr > qrow) sv = -1e30f;
            s[rf][cf][j] = sv;
            mx = fmaxf(mx, sv);
          }
          tm[j] = mx;
        }
#pragma unroll
        for (int mm = 1; mm < 16; mm <<= 1)
#pragma unroll
          for (int j = 0; j < 4; ++j) tm[j] = fmaxf(tm[j], __shfl_xor(tm[j], mm));
        f32x4 mnew, corr, ps;
#pragma unroll
        for (int j = 0; j < 4; ++j) {
          mnew[j] = fmaxf(mrun[rf][j], tm[j]);
          corr[j] = __expf(mrun[rf][j] - mnew[j]);
          mrun[rf][j] = mnew[j];
          ps[j] = 0.f;
        }
#pragma unroll
        for (int cf = 0; cf < 4; ++cf)
#pragma unroll
          for (int j = 0; j < 4; ++j) {
            const float p = __expf(s[rf][cf][j] - mnew[j]);
            ps[j] += p;
            Pw[(rf * 16 + lg * 4 + j) * 68 + cf * 16 + lr] = f2bs(p);
          }
#pragma unroll
        for (int mm = 1; mm < 16; mm <<= 1)
#pragma unroll
          for (int j = 0; j < 4; ++j) ps[j] += __shfl_xor(ps[j], mm);
#pragma unroll
        for (int j = 0; j < 4; ++j) lrun[rf][j] = lrun[rf][j] * corr[j] + ps[j];
#pragma unroll
        for (int vf = 0; vf < 4; ++vf)
#pragma unroll
          for (int j = 0; j < 4; ++j) o[rf][vf][j] *= corr[j];
      }
      // same-wave LDS write->read fence
      asm volatile("s_waitcnt lgkmcnt(0)" ::: "memory");
      __builtin_amdgcn_sched_barrier(0);
      short8 pa[2][2], vb[4][2];
#pragma unroll
      for (int rf = 0; rf < 2; ++rf)
#pragma unroll
        for (int k2 = 0; k2 < 2; ++k2)
          pa[rf][k2] = ld8(&Pw[(rf * 16 + lr) * 68 + k2 * 32 + lg * 8]);
#pragma unroll
      for (int vf = 0; vf < 4; ++vf)
#pragma unroll
        for (int k2 = 0; k2 < 2; ++k2)
          vb[vf][k2] = ld8(&Vt[bb][(vf * 16 + lr) * 68 + k2 * 32 + lg * 8]);
#pragma unroll
      for (int rf = 0; rf < 2; ++rf)
#pragma unroll
        for (int vf = 0; vf < 4; ++vf)
#pragma unroll
          for (int k2 = 0; k2 < 2; ++k2)
            o[rf][vf] = __builtin_amdgcn_mfma_f32_16x16x32_bf16(
                pa[rf][k2], vb[vf][k2], o[rf][vf], 0, 0, 0);
    }
    asm volatile("s_waitcnt vmcnt(0)" ::: "memory");
    if (nx < ntb) {
      const int kvl = wave * 8 + kr;
#pragma unroll
      for (int j = 0; j < 8; ++j)
        Vt[nx & 1][((lane & 7) * 8 + j) * 68 + kvl] = vreg[j];
    }
    __syncthreads();
  }

#pragma unroll
  for (int rf = 0; rf < 2; ++rf) {
    f32x4 inv;
#pragma unroll
    for (int j = 0; j < 4; ++j) inv[j] = 1.0f / lrun[rf][j];
#pragma unroll
    for (int vf = 0; vf < 4; ++vf)
#pragma unroll
      for (int j = 0; j < 4; ++j)
        yp[(size_t)(qw + rf * 16 + lg * 4 + j) * Cn + vf * 16 + lr] =
            f2bs(o[rf][vf][j] * inv[j]);
  }
}

// ---------- launch ----------
extern "C" void kernel_launch(void* const* d_in, const int* in_sizes, int n_in,
                              void* d_out, int out_size, void* d_ws, size_t ws_size,
                              hipStream_t stream) {
  const float* observations = (const float*)d_in[0];
  const float* obs_W = (const float*)d_in[1];
  const float* obs_b = (const float*)d_in[2];
  const float* pos_emb = (const float*)d_in[3];
  const float* ln1_w = (const float*)d_in[4];
  const float* ln1_b = (const float*)d_in[5];
  const float* Wq = (const float*)d_in[6];
  const float* bq = (const float*)d_in[7];
  const float* Wk = (const float*)d_in[8];
  const float* bk = (const float*)d_in[9];
  const float* Wv = (const float*)d_in[10];
  const float* bv = (const float*)d_in[11];
  const float* Wo = (const float*)d_in[12];
  const float* bo = (const float*)d_in[13];
  const float* ln2_w = (const float*)d_in[14];
  const float* ln2_b = (const float*)d_in[15];
  const float* W1 = (const float*)d_in[16];
  const float* b1 = (const float*)d_in[17];
  const float* W2 = (const float*)d_in[18];
  const float* b2 = (const float*)d_in[19];
  const float* lnf_w = (const float*)d_in[20];
  const float* lnf_b = (const float*)d_in[21];
  float* out = (float*)d_out;

  char* ws = (char*)d_ws;
  auto alloc = [&](size_t bytes) -> void* {
    void* p = (void*)ws;
    ws += (bytes + 255) & ~(size_t)255;
    return p;
  };
  const size_t WCC = (size_t)Cn * Cn;        // 262144
  const size_t WCF = (size_t)Cn * 4 * Cn;    // 1048576

  float* xf = (float*)alloc((size_t)Mn * Cn * 4);
  short* hbf = (short*)alloc((size_t)Mn * Cn * 2);
  short* qkvb = (short*)alloc((size_t)Mn * SQk * 2);
  short* ybf = (short*)alloc((size_t)Mn * Cn * 2);
  short* gbf = (short*)alloc((size_t)Mn * 4 * Cn * 2);   // also aliases partWo
  float* partM = (float*)alloc((size_t)2 * Mn * Cn * 4); // MLP2 partials
  short* obsbf = (short*)alloc((size_t)Mn * ODn * 2);
  short* obsWt = (short*)alloc((size_t)ODn * Cn * 2);
  short* wqkvT = (short*)alloc((size_t)Ln * 3 * WCC * 2);
  short* woT = (short*)alloc((size_t)Ln * WCC * 2);
  short* w1T = (short*)alloc((size_t)Ln * WCF * 2);
  short* w2T = (short*)alloc((size_t)Ln * WCF * 2);
  float* bqkv = (float*)alloc((size_t)Ln * SQk * 4);
  if ((size_t)(ws - (char*)d_ws) > ws_size) return;  // ws too small: bail
  float* partWo = (float*)gbf;  // lifetimes disjoint: [Wo, lnred2] vs [MLP1, MLP2]

  // weight casts/transposes (batched) + bias concat
  wtrans4_kernel<<<dim3(16, 16, 24), 256, 0, stream>>>(Wq, Wk, Wv, Wo, wqkvT, woT);
  wtransL_kernel<<<dim3(16, 24, 1), 256, 0, stream>>>(obs_W, obsWt, ODn, Cn);
  wtransL_kernel<<<dim3(64, 16, 6), 256, 0, stream>>>(W1, w1T, Cn, 4 * Cn);
  wtransL_kernel<<<dim3(16, 64, 6), 256, 0, stream>>>(W2, w2T, 4 * Cn, Cn);
  bcat_kernel<<<(Ln * SQk) / 256, 256, 0, stream>>>(bq, bk, bv, bqkv);
  cast_kernel<<<(Mn * ODn) / 1024, 256, 0, stream>>>(
      (const float4*)observations, (sh4*)obsbf);

  // obs embedding: gelu(obs@W+b) + pos -> xf (fp32)
  gemm_kernel<2, 1><<<dim3(Cn / 128, Mn / 128), 256, 0, stream>>>(
      obsbf, obsWt, obs_b, nullptr, xf, pos_emb, ODn, Cn);

  // layer 0 ln1 (no partials yet)
  ln_kernel<short><<<Mn, 256, 0, stream>>>(xf, ln1_w, ln1_b, hbf);

  for (int i = 0; i < Ln; ++i) {
    // fused QKV: N = 1536
    gemm_kernel<0, 1><<<dim3(12, 64), 256, 0, stream>>>(
        hbf, wqkvT + i * 3 * WCC, bqkv + i * SQk, qkvb, nullptr, nullptr, Cn, SQk);
    attn_kernel<<<dim3(4, Bn * Hn), 512, 0, stream>>>(qkvb, ybf);
    // Wo: split-K=2 -> fp32 partials (no atomics)
    gemm_kernel<4, 2><<<dim3(4, 64, 2), 256, 0, stream>>>(
        ybf, woT + i * WCC, bo + i * Cn, nullptr, partWo, nullptr, Cn, Cn);
    // ln2 fused with partial reduction; updates xf
    lnred_kernel<2, short, true><<<Mn, 256, 0, stream>>>(
        xf, partWo, ln2_w + i * Cn, ln2_b + i * Cn, hbf);
    gemm_kernel<1, 1><<<dim3(16, 64), 256, 0, stream>>>(
        hbf, w1T + i * WCF, b1 + i * 4 * Cn, gbf, nullptr, nullptr, Cn, 4 * Cn);
    // MLP2: K = 2048, split-K=2 -> fp32 partials
    gemm_kernel<4, 2><<<dim3(4, 64, 2), 256, 0, stream>>>(
        gbf, w2T + i * WCF, b2 + i * Cn, nullptr, partM, nullptr, 4 * Cn, Cn);
    if (i < Ln - 1) {
      // next layer's ln1 fused with MLP2 partial reduction; updates xf
      lnred_kernel<2, short, true><<<Mn, 256, 0, stream>>>(
          xf, partM, ln1_w + (i + 1) * Cn, ln1_b + (i + 1) * Cn, hbf);
    } else {
      // final LN fused with last MLP2 partial reduction -> fp32 out
      lnred_kernel<2, float, false><<<Mn, 256, 0, stream>>>(
          xf, partM, lnf_w, lnf_b, out);
    }
  }
}